// Round 1
// baseline (981.549 us; speedup 1.0000x reference)
//
#include <hip/hip_runtime.h>
#include <math.h>

// Problem constants
constexpr int B_  = 8;
constexpr int NU  = 256;
constexpr int NA  = 256;
constexpr int UD  = 128;   // user/ant feature dim
constexpr int ED  = 64;    // edge feature dim
constexpr int H   = 8;     // heads
constexpr int HD  = 64;    // head dim
constexpr int HID = 512;   // H*HD
constexpr float SLOPE = 0.2f;
constexpr float SCALE = 0.125f;  // 1/sqrt(64)

// ws layout (in floats)
constexpr size_t WS_UALL  = 0;          // [B][NU][512]  user @ Wu (all heads)
constexpr size_t WS_AALL  = 1048576;    // [B][NA][512]  ant @ Wa
constexpr size_t WS_UBASE = 2097152;    // [B][NU][512]  user @ Wres
constexpr size_t WS_ALPHA = 3145728;    // [B][NA][NU][H] softmax weights
// total floats: 3*1048576 + 4194304 = 7340032  (28 MB)

// ---------------------------------------------------------------------------
// Kernel A: small projections. grid (512, 3), 256 thr. Each block: 4 rows.
// job 0: U_all = user @ Wu ; job 1: A_all = ant @ Wa ; job 2: ubase = user @ Wres
// ---------------------------------------------------------------------------
__global__ __launch_bounds__(256) void prep_kernel(
    const float* __restrict__ user, const float* __restrict__ ant,
    const float* __restrict__ Wu, const float* __restrict__ Wa,
    const float* __restrict__ Wres, float* __restrict__ ws)
{
  const int job = blockIdx.y;
  const int r0  = blockIdx.x * 4;
  const int t   = threadIdx.x;

  const float* X = (job == 1) ? ant : user;
  const float* W = (job == 0) ? Wu : (job == 1) ? Wa : Wres;
  float* out = ws + (job == 0 ? WS_UALL : (job == 1 ? WS_AALL : WS_UBASE));

  __shared__ float xs[4][UD];
  #pragma unroll
  for (int i = 0; i < 2; ++i) {
    int idx = i * 256 + t;                       // 0..511
    xs[idx >> 7][idx & 127] = X[(size_t)(r0 + (idx >> 7)) * UD + (idx & 127)];
  }
  __syncthreads();

  const int j0 = 2 * t;                          // output column pair
  const float* wp;
  int wstride;
  if (job < 2) { wp = W + (size_t)(j0 >> 6) * (UD * HD) + (j0 & 63); wstride = HD; }
  else         { wp = W + j0;                                        wstride = HID; }

  float2 acc[4];
  #pragma unroll
  for (int r = 0; r < 4; ++r) acc[r] = make_float2(0.f, 0.f);

  for (int k = 0; k < UD; ++k) {
    float2 w = *(const float2*)(wp + (size_t)k * wstride);
    #pragma unroll
    for (int r = 0; r < 4; ++r) {
      float x = xs[r][k];
      acc[r].x += x * w.x;
      acc[r].y += x * w.y;
    }
  }
  #pragma unroll
  for (int r = 0; r < 4; ++r)
    *(float2*)(out + (size_t)(r0 + r) * HID + j0) = acc[r];
}

// ---------------------------------------------------------------------------
// Kernel B: per (b,u): scores for all (a,h), softmax, alpha out, user_out.
// grid = B*NU blocks, 256 threads. thread t: head h=t>>5, lane l=t&31,
// owns output cols j0=h*64+2l, j0+1.
// ---------------------------------------------------------------------------
__global__ __launch_bounds__(256, 2) void score_user_kernel(
    const float* __restrict__ edge, const float* __restrict__ We,
    const float* __restrict__ av, float* __restrict__ ws,
    float* __restrict__ out)
{
  const int bid = blockIdx.x;          // b*NU + u
  const int b = bid >> 8, u = bid & 255;
  const int t = threadIdx.x;
  const int h = t >> 5, l = t & 31;
  const int j0 = h * HD + 2 * l;

  __shared__ float elds[NA * ED];      // 64 KB: edge[b,u,:,:]
  __shared__ float sc[NA * 9];         // padded [a][h] scores -> probs
  __shared__ float gu[H * ED];         // alpha-weighted edge sums per head

  // W columns for this thread's two output dims (reused in stages 2 & 5)
  float2 wcol[ED];
  {
    const float* wp = We + (size_t)h * (ED * HD) + 2 * l;
    #pragma unroll
    for (int e = 0; e < ED; ++e) wcol[e] = *(const float2*)(wp + e * HD);
  }
  const float2 avv = *(const float2*)(av + h * HD + 2 * l);

  // stage 1: edge tile -> LDS (coalesced float4)
  {
    const float4* ep = (const float4*)(edge + (size_t)bid * NA * ED);
    float4* el4 = (float4*)elds;
    #pragma unroll
    for (int i = 0; i < 16; ++i) el4[i * 256 + t] = ep[i * 256 + t];
  }
  __syncthreads();

  const float* Uall = ws + WS_UALL;
  const float* Aall = ws + WS_AALL;
  const float2 cu = *(const float2*)(Uall + (size_t)bid * HID + j0);

  // stage 2: scores
  {
    const float4* el4 = (const float4*)elds;
    float2 ca_next = *(const float2*)(Aall + ((size_t)b * NA + 0) * HID + j0);
    for (int a = 0; a < NA; ++a) {
      float2 ca = ca_next;
      int an = (a + 1 < NA) ? (a + 1) : (NA - 1);
      ca_next = *(const float2*)(Aall + ((size_t)b * NA + an) * HID + j0);
      float s0 = cu.x + ca.x;
      float s1 = cu.y + ca.y;
      #pragma unroll
      for (int e4 = 0; e4 < 16; ++e4) {
        float4 ev = el4[a * 16 + e4];
        s0 += ev.x * wcol[4*e4+0].x; s1 += ev.x * wcol[4*e4+0].y;
        s0 += ev.y * wcol[4*e4+1].x; s1 += ev.y * wcol[4*e4+1].y;
        s0 += ev.z * wcol[4*e4+2].x; s1 += ev.z * wcol[4*e4+2].y;
        s0 += ev.w * wcol[4*e4+3].x; s1 += ev.w * wcol[4*e4+3].y;
      }
      s0 = (s0 >= 0.f) ? s0 : SLOPE * s0;
      s1 = (s1 >= 0.f) ? s1 : SLOPE * s1;
      float v = s0 * avv.x + s1 * avv.y;
      #pragma unroll
      for (int off = 16; off >= 1; off >>= 1) v += __shfl_xor(v, off);
      if (l == 0) sc[a * 9 + h] = v * SCALE;
    }
  }
  __syncthreads();

  // stage 3: softmax over a (per head). 32 lanes/head, 8 values each.
  {
    float vals[8];
    float m = -1e30f;
    #pragma unroll
    for (int i = 0; i < 8; ++i) {
      vals[i] = sc[(l * 8 + i) * 9 + h];
      m = fmaxf(m, vals[i]);
    }
    #pragma unroll
    for (int off = 16; off >= 1; off >>= 1) m = fmaxf(m, __shfl_xor(m, off));
    float sum = 0.f;
    #pragma unroll
    for (int i = 0; i < 8; ++i) { vals[i] = __expf(vals[i] - m); sum += vals[i]; }
    #pragma unroll
    for (int off = 16; off >= 1; off >>= 1) sum += __shfl_xor(sum, off);
    float inv = 1.0f / sum;
    #pragma unroll
    for (int i = 0; i < 8; ++i) sc[(l * 8 + i) * 9 + h] = vals[i] * inv;
  }
  __syncthreads();

  // write alpha to ws: layout [b][a][u][h] (coalesced reads in ant kernel)
  {
    float* ag = ws + WS_ALPHA;
    #pragma unroll
    for (int i = 0; i < 8; ++i) {
      int idx = i * 256 + t;                 // 0..2047
      int a = idx >> 3, hh = idx & 7;
      ag[(((size_t)b * NA + a) * NU + u) * H + hh] = sc[a * 9 + hh];
    }
  }

  // stage 4: user accumulation: Guser (edge space) + alpha@A (head space)
  float g0 = 0.f, g1 = 0.f, pa0 = 0.f, pa1 = 0.f;
  for (int a = 0; a < NA; ++a) {
    float p = sc[a * 9 + h];
    float2 ev = *(const float2*)(elds + a * ED + 2 * l);
    g0 += p * ev.x; g1 += p * ev.y;
    float2 aa = *(const float2*)(Aall + ((size_t)b * NA + a) * HID + j0);
    pa0 += p * aa.x; pa1 += p * aa.y;
  }
  gu[h * ED + 2 * l]     = g0;
  gu[h * ED + 2 * l + 1] = g1;
  __syncthreads();

  // stage 5: project Guser by We, add alpha@A and user@Wres, write out
  {
    const float* ubase = ws + WS_UBASE;
    float o0 = pa0, o1 = pa1;
    #pragma unroll
    for (int e = 0; e < ED; ++e) {
      float gv = gu[h * ED + e];
      o0 += gv * wcol[e].x;
      o1 += gv * wcol[e].y;
    }
    float2 ub = *(const float2*)(ubase + (size_t)bid * HID + j0);
    *(float2*)(out + (size_t)bid * HID + j0) = make_float2(o0 + ub.x, o1 + ub.y);
  }
}

// ---------------------------------------------------------------------------
// Kernel C: per (b,a): ant_out = sum_u alpha*(U + E).
// Gant accumulated in edge space, alpha@U in head space; project at end.
// grid = B*NA blocks, 256 threads.
// ---------------------------------------------------------------------------
__global__ __launch_bounds__(256, 2) void ant_kernel(
    const float* __restrict__ edge, const float* __restrict__ We,
    const float* __restrict__ ws, float* __restrict__ out)
{
  const int bid = blockIdx.x;          // b*NA + a
  const int b = bid >> 8, a = bid & 255;
  const int t = threadIdx.x;
  const int h = t >> 5, l = t & 31;
  const int j0 = h * HD + 2 * l;

  __shared__ float elds[32 * ED];      // 8 KB: 32 edge rows
  __shared__ float plds[32 * H];       // 1 KB: alpha chunk
  __shared__ float ga[H * ED];

  float2 wcol[ED];
  {
    const float* wp = We + (size_t)h * (ED * HD) + 2 * l;
    #pragma unroll
    for (int e = 0; e < ED; ++e) wcol[e] = *(const float2*)(wp + e * HD);
  }

  const float* Uall = ws + WS_UALL;
  const float* ag = ws + WS_ALPHA + ((size_t)b * NA + a) * NU * H;

  float g0 = 0.f, g1 = 0.f, pu0 = 0.f, pu1 = 0.f;

  for (int u0 = 0; u0 < NU; u0 += 32) {
    plds[t] = ag[(size_t)u0 * H + t];  // 256 contiguous floats: [uu][h]
    #pragma unroll
    for (int i = 0; i < 2; ++i) {
      int idx = i * 256 + t;           // 0..511 float4 slots (32 rows x 16)
      int uu = idx >> 4, e4 = idx & 15;
      ((float4*)elds)[idx] =
          *(const float4*)(edge + (((size_t)b * NU + u0 + uu) * NA + a) * ED + e4 * 4);
    }
    __syncthreads();
    for (int uu = 0; uu < 32; ++uu) {
      float p = plds[uu * H + h];
      float2 ev = *(const float2*)(elds + uu * ED + 2 * l);
      g0 += p * ev.x; g1 += p * ev.y;
      float2 uv = *(const float2*)(Uall + ((size_t)b * NU + u0 + uu) * HID + j0);
      pu0 += p * uv.x; pu1 += p * uv.y;
    }
    __syncthreads();
  }

  ga[h * ED + 2 * l]     = g0;
  ga[h * ED + 2 * l + 1] = g1;
  __syncthreads();

  float o0 = pu0, o1 = pu1;
  #pragma unroll
  for (int e = 0; e < ED; ++e) {
    float gv = ga[h * ED + e];
    o0 += gv * wcol[e].x;
    o1 += gv * wcol[e].y;
  }
  *(float2*)(out + (size_t)(B_ * NU) * HID + (size_t)bid * HID + j0) =
      make_float2(o0, o1);
}

// ---------------------------------------------------------------------------
extern "C" void kernel_launch(void* const* d_in, const int* in_sizes, int n_in,
                              void* d_out, int out_size, void* d_ws, size_t ws_size,
                              hipStream_t stream) {
  const float* user = (const float*)d_in[0];
  const float* ant  = (const float*)d_in[1];
  const float* edge = (const float*)d_in[2];
  const float* Wu   = (const float*)d_in[3];
  const float* Wa   = (const float*)d_in[4];
  const float* We   = (const float*)d_in[5];
  const float* av   = (const float*)d_in[6];
  const float* Wres = (const float*)d_in[7];
  float* out = (float*)d_out;
  float* ws  = (float*)d_ws;

  prep_kernel<<<dim3(512, 3), 256, 0, stream>>>(user, ant, Wu, Wa, Wres, ws);
  score_user_kernel<<<dim3(B_ * NU), 256, 0, stream>>>(edge, We, av, ws, out);
  ant_kernel<<<dim3(B_ * NA), 256, 0, stream>>>(edge, We, ws, out);
}

// Round 2
// 730.725 us; speedup vs baseline: 1.3433x; 1.3433x over previous
//
#include <hip/hip_runtime.h>
#include <math.h>

// Problem constants
constexpr int B_  = 8;
constexpr int NU  = 256;
constexpr int NA  = 256;
constexpr int UD  = 128;   // user/ant feature dim
constexpr int ED  = 64;    // edge feature dim
constexpr int H   = 8;     // heads
constexpr int HD  = 64;    // head dim
constexpr int HID = 512;   // H*HD
constexpr float SLOPE = 0.2f;
constexpr float SCALE = 0.125f;  // 1/sqrt(64)

// ws layout (in floats)
constexpr size_t WS_UALL  = 0;          // [B][NU][512]  user @ Wu (all heads)
constexpr size_t WS_AALL  = 1048576;    // [B][NA][512]  ant @ Wa
constexpr size_t WS_UBASE = 2097152;    // [B][NU][512]  user @ Wres
constexpr size_t WS_ALPHA = 3145728;    // [B][NA][NU][H] softmax weights

typedef __attribute__((ext_vector_type(8))) short short8v;  // 8 bf16
typedef __attribute__((ext_vector_type(4))) float f32x4;

static __device__ __forceinline__ unsigned short f2bf(float f) {
  unsigned int u = __float_as_uint(f);
  unsigned int r = (u + 0x7fffu + ((u >> 16) & 1u)) >> 16;   // RNE
  return (unsigned short)r;
}

// ---------------------------------------------------------------------------
// Kernel A: small projections. grid (512, 3), 256 thr. Each block: 4 rows.
// ---------------------------------------------------------------------------
__global__ __launch_bounds__(256) void prep_kernel(
    const float* __restrict__ user, const float* __restrict__ ant,
    const float* __restrict__ Wu, const float* __restrict__ Wa,
    const float* __restrict__ Wres, float* __restrict__ ws)
{
  const int job = blockIdx.y;
  const int r0  = blockIdx.x * 4;
  const int t   = threadIdx.x;

  const float* X = (job == 1) ? ant : user;
  const float* W = (job == 0) ? Wu : (job == 1) ? Wa : Wres;
  float* out = ws + (job == 0 ? WS_UALL : (job == 1 ? WS_AALL : WS_UBASE));

  __shared__ float xs[4][UD];
  #pragma unroll
  for (int i = 0; i < 2; ++i) {
    int idx = i * 256 + t;
    xs[idx >> 7][idx & 127] = X[(size_t)(r0 + (idx >> 7)) * UD + (idx & 127)];
  }
  __syncthreads();

  const int j0 = 2 * t;
  const float* wp;
  int wstride;
  if (job < 2) { wp = W + (size_t)(j0 >> 6) * (UD * HD) + (j0 & 63); wstride = HD; }
  else         { wp = W + j0;                                        wstride = HID; }

  float2 acc[4];
  #pragma unroll
  for (int r = 0; r < 4; ++r) acc[r] = make_float2(0.f, 0.f);

  for (int k = 0; k < UD; ++k) {
    float2 w = *(const float2*)(wp + (size_t)k * wstride);
    #pragma unroll
    for (int r = 0; r < 4; ++r) {
      float x = xs[r][k];
      acc[r].x += x * w.x;
      acc[r].y += x * w.y;
    }
  }
  #pragma unroll
  for (int r = 0; r < 4; ++r)
    *(float2*)(out + (size_t)(r0 + r) * HID + j0) = acc[r];
}

// ---------------------------------------------------------------------------
// Kernel B: per (b,u). MFMA score phase + softmax + fp32 accumulation.
// 256 threads = 4 waves. Wave w owns output cols [128w, 128w+128) (heads 2w,2w+1).
// ---------------------------------------------------------------------------
__global__ __launch_bounds__(256) void score_user_kernel(
    const float* __restrict__ edge, const float* __restrict__ We,
    const float* __restrict__ av, float* __restrict__ ws,
    float* __restrict__ out)
{
  const int bid = blockIdx.x;          // b*NU + u
  const int b = bid >> 8, u = bid & 255;
  const int t = threadIdx.x;

  __shared__ __align__(16) char buf[8192];   // phase1: bf16 a-tile (4KB); phase4: fp32 chunk (8KB)
  __shared__ float sc[NA * 9];               // [a][h] scores -> probs (pad 9)
  __shared__ float gu[H * ED];               // alpha-weighted edge sums per head

  const float* Uall = ws + WS_UALL;
  const float* Aall = ws + WS_AALL;

  // ---- wave/lane decomposition for MFMA phase ----
  const int w    = t >> 6;          // wave 0..3
  const int lane = t & 63;
  const int l16  = lane & 15;
  const int kgrp = lane >> 4;       // 0..3

  // Hoist B-fragments of We (bf16) + U cols + av for this wave's 128 cols.
  short8v wf[8][2];
  float   ucol[8];
  float   avv[8];
  #pragma unroll
  for (int n = 0; n < 8; ++n) {
    const int j = 128 * w + 16 * n + l16;     // global col
    const int hh = j >> 6, d = j & 63;
    const float* wp = We + (size_t)hh * (ED * HD) + d;
    #pragma unroll
    for (int c = 0; c < 2; ++c) {
      #pragma unroll
      for (int i = 0; i < 8; ++i)
        wf[n][c][i] = (short)f2bf(wp[(size_t)(c * 32 + kgrp * 8 + i) * HD]);
    }
    ucol[n] = Uall[(size_t)bid * HID + j];
    avv[n]  = av[hh * HD + d];
  }

  short* ebuf = (short*)buf;  // [32][64] bf16, XOR-swizzled

  // ---- phase 1: scores via MFMA, 8 a-tiles of 32 ----
  for (int a0 = 0; a0 < NA; a0 += 32) {
    __syncthreads();   // prior tile's LDS reads done
    // stage edge a-tile fp32->bf16 into swizzled LDS
    {
      const float4* ep = (const float4*)(edge + ((size_t)bid * NA + a0) * ED);
      #pragma unroll
      for (int i = 0; i < 2; ++i) {
        int s = i * 256 + t;               // 512 float4 slots (32 rows x 16)
        int row = s >> 4, c4 = s & 15;
        float4 v = ep[s];
        ushort4 bv = make_ushort4(f2bf(v.x), f2bf(v.y), f2bf(v.z), f2bf(v.w));
        int byte = row * 128 + c4 * 8;
        byte ^= (row & 7) << 4;
        *(ushort4*)((char*)ebuf + byte) = bv;
      }
    }
    __syncthreads();

    // A-fragments from LDS
    short8v af[2][2];
    #pragma unroll
    for (int m = 0; m < 2; ++m) {
      #pragma unroll
      for (int c = 0; c < 2; ++c) {
        int row = m * 16 + l16;
        int byte = row * 128 + (c * 32 + kgrp * 8) * 2;
        byte ^= (row & 7) << 4;
        af[m][c] = *(const short8v*)((const char*)ebuf + byte);
      }
    }

    f32x4 acc[2][8];
    #pragma unroll
    for (int m = 0; m < 2; ++m)
      #pragma unroll
      for (int n = 0; n < 8; ++n)
        acc[m][n] = (f32x4)(0.f);

    #pragma unroll
    for (int c = 0; c < 2; ++c)
      #pragma unroll
      for (int m = 0; m < 2; ++m)
        #pragma unroll
        for (int n = 0; n < 8; ++n)
          acc[m][n] = __builtin_amdgcn_mfma_f32_16x16x32_bf16(
              af[m][c], wf[n][c], acc[m][n], 0, 0, 0);

    // epilogue: add U + A, leaky, dot with av, reduce over 16-lane col group
    const float* Abase = Aall + ((size_t)b * NA + a0) * HID + 128 * w + l16;
    #pragma unroll
    for (int m = 0; m < 2; ++m) {
      #pragma unroll
      for (int q = 0; q < 4; ++q) {
        const int a_loc = m * 16 + kgrp * 4 + q;
        const float* Ar = Abase + (size_t)a_loc * HID;
        float h0 = 0.f, h1 = 0.f;
        #pragma unroll
        for (int n = 0; n < 8; ++n) {
          float s = acc[m][n][q] + ucol[n] + Ar[16 * n];
          s = (s >= 0.f) ? s : SLOPE * s;
          float v = s * avv[n];
          if (n < 4) h0 += v; else h1 += v;
        }
        #pragma unroll
        for (int off = 8; off >= 1; off >>= 1) {
          h0 += __shfl_xor(h0, off);
          h1 += __shfl_xor(h1, off);
        }
        if (l16 == 0) sc[(a0 + a_loc) * 9 + 2 * w]     = h0 * SCALE;
        if (l16 == 1) sc[(a0 + a_loc) * 9 + 2 * w + 1] = h1 * SCALE;
      }
    }
  }
  __syncthreads();

  // ---- phase 2: softmax over a (per head). h = t>>5, l = t&31 ----
  const int h = t >> 5, l = t & 31;
  {
    float vals[8];
    float m = -1e30f;
    #pragma unroll
    for (int i = 0; i < 8; ++i) {
      vals[i] = sc[(l * 8 + i) * 9 + h];
      m = fmaxf(m, vals[i]);
    }
    #pragma unroll
    for (int off = 16; off >= 1; off >>= 1) m = fmaxf(m, __shfl_xor(m, off));
    float sum = 0.f;
    #pragma unroll
    for (int i = 0; i < 8; ++i) { vals[i] = __expf(vals[i] - m); sum += vals[i]; }
    #pragma unroll
    for (int off = 16; off >= 1; off >>= 1) sum += __shfl_xor(sum, off);
    float inv = 1.0f / sum;
    #pragma unroll
    for (int i = 0; i < 8; ++i) sc[(l * 8 + i) * 9 + h] = vals[i] * inv;
  }
  __syncthreads();

  // ---- phase 3: alpha -> ws [b][a][u][h] for the ant kernel ----
  {
    float* ag = ws + WS_ALPHA;
    #pragma unroll
    for (int i = 0; i < 8; ++i) {
      int idx = i * 256 + t;
      int a = idx >> 3, hh = idx & 7;
      ag[(((size_t)b * NA + a) * NU + u) * H + hh] = sc[a * 9 + hh];
    }
  }

  // ---- phase 4: user accumulation. thread (h,l): e0=l, e1=l+32; j0=h*64+2l ----
  const int j0 = h * HD + 2 * l;
  float g0 = 0.f, g1 = 0.f, pa0 = 0.f, pa1 = 0.f;
  float* echunk = (float*)buf;    // [32][64] fp32
  for (int a0 = 0; a0 < NA; a0 += 32) {
    __syncthreads();
    {
      const float4* ep = (const float4*)(edge + ((size_t)bid * NA + a0) * ED);
      ((float4*)echunk)[t]       = ep[t];
      ((float4*)echunk)[256 + t] = ep[256 + t];
    }
    __syncthreads();
    for (int aa = 0; aa < 32; ++aa) {
      float p = sc[(a0 + aa) * 9 + h];
      g0 += p * echunk[aa * 64 + l];
      g1 += p * echunk[aa * 64 + l + 32];
      float2 av2 = *(const float2*)(Aall + ((size_t)b * NA + a0 + aa) * HID + j0);
      pa0 += p * av2.x;
      pa1 += p * av2.y;
    }
  }
  gu[h * ED + l]      = g0;
  gu[h * ED + l + 32] = g1;
  __syncthreads();

  // ---- phase 5: project gu by We (fp32 from global, L2-hot), add bases ----
  {
    const float* ubase = ws + WS_UBASE;
    float o0 = pa0, o1 = pa1;
    const float* wp = We + (size_t)h * (ED * HD) + 2 * l;
    #pragma unroll
    for (int e = 0; e < ED; ++e) {
      float gv = gu[h * ED + e];
      float2 wv = *(const float2*)(wp + (size_t)e * HD);
      o0 += gv * wv.x;
      o1 += gv * wv.y;
    }
    float2 ub = *(const float2*)(ubase + (size_t)bid * HID + j0);
    *(float2*)(out + (size_t)bid * HID + j0) = make_float2(o0 + ub.x, o1 + ub.y);
  }
}

// ---------------------------------------------------------------------------
// Kernel C: per (b,a): ant_out = sum_u alpha*(U + E).
// ---------------------------------------------------------------------------
__global__ __launch_bounds__(256, 2) void ant_kernel(
    const float* __restrict__ edge, const float* __restrict__ We,
    const float* __restrict__ ws, float* __restrict__ out)
{
  const int bid = blockIdx.x;          // b*NA + a
  const int b = bid >> 8, a = bid & 255;
  const int t = threadIdx.x;
  const int h = t >> 5, l = t & 31;
  const int j0 = h * HD + 2 * l;

  __shared__ float elds[32 * ED];
  __shared__ float plds[32 * H];
  __shared__ float ga[H * ED];

  float2 wcol[ED];
  {
    const float* wp = We + (size_t)h * (ED * HD) + 2 * l;
    #pragma unroll
    for (int e = 0; e < ED; ++e) wcol[e] = *(const float2*)(wp + e * HD);
  }

  const float* Uall = ws + WS_UALL;
  const float* ag = ws + WS_ALPHA + ((size_t)b * NA + a) * NU * H;

  float g0 = 0.f, g1 = 0.f, pu0 = 0.f, pu1 = 0.f;

  for (int u0 = 0; u0 < NU; u0 += 32) {
    plds[t] = ag[(size_t)u0 * H + t];
    #pragma unroll
    for (int i = 0; i < 2; ++i) {
      int idx = i * 256 + t;
      int uu = idx >> 4, e4 = idx & 15;
      ((float4*)elds)[idx] =
          *(const float4*)(edge + (((size_t)b * NU + u0 + uu) * NA + a) * ED + e4 * 4);
    }
    __syncthreads();
    for (int uu = 0; uu < 32; ++uu) {
      float p = plds[uu * H + h];
      float2 ev = *(const float2*)(elds + uu * ED + 2 * l);
      g0 += p * ev.x; g1 += p * ev.y;
      float2 uv = *(const float2*)(Uall + ((size_t)b * NU + u0 + uu) * HID + j0);
      pu0 += p * uv.x; pu1 += p * uv.y;
    }
    __syncthreads();
  }

  ga[h * ED + 2 * l]     = g0;
  ga[h * ED + 2 * l + 1] = g1;
  __syncthreads();

  float o0 = pu0, o1 = pu1;
  #pragma unroll
  for (int e = 0; e < ED; ++e) {
    float gv = ga[h * ED + e];
    o0 += gv * wcol[e].x;
    o1 += gv * wcol[e].y;
  }
  *(float2*)(out + (size_t)(B_ * NU) * HID + (size_t)bid * HID + j0) =
      make_float2(o0, o1);
}

// ---------------------------------------------------------------------------
extern "C" void kernel_launch(void* const* d_in, const int* in_sizes, int n_in,
                              void* d_out, int out_size, void* d_ws, size_t ws_size,
                              hipStream_t stream) {
  const float* user = (const float*)d_in[0];
  const float* ant  = (const float*)d_in[1];
  const float* edge = (const float*)d_in[2];
  const float* Wu   = (const float*)d_in[3];
  const float* Wa   = (const float*)d_in[4];
  const float* We   = (const float*)d_in[5];
  const float* av   = (const float*)d_in[6];
  const float* Wres = (const float*)d_in[7];
  float* out = (float*)d_out;
  float* ws  = (float*)d_ws;

  prep_kernel<<<dim3(512, 3), 256, 0, stream>>>(user, ant, Wu, Wa, Wres, ws);
  score_user_kernel<<<dim3(B_ * NU), 256, 0, stream>>>(edge, We, av, ws, out);
  ant_kernel<<<dim3(B_ * NA), 256, 0, stream>>>(edge, We, ws, out);
}

// Round 3
// 662.541 us; speedup vs baseline: 1.4815x; 1.1029x over previous
//
#include <hip/hip_runtime.h>
#include <math.h>

// Problem constants
constexpr int B_  = 8;
constexpr int NU  = 256;
constexpr int NA  = 256;
constexpr int UD  = 128;
constexpr int ED  = 64;
constexpr int H   = 8;
constexpr int HD  = 64;
constexpr int HID = 512;
constexpr float SLOPE = 0.2f;
constexpr float SCALE = 0.125f;

// ws layout (floats)
constexpr size_t WS_UT    = 0;          // [B][512][256]  (user@Wu)^T : UT[b][j][u]
constexpr size_t WS_AT    = 1048576;    // [B][512][256]  (ant@Wa)^T  : AT[b][j][a]
constexpr size_t WS_UBASE = 2097152;    // [B][NU][512]   user@Wres (row-major)
constexpr size_t WS_ALPHA = 3145728;    // [B][NA][NU][H] softmax weights

typedef __attribute__((ext_vector_type(8))) short short8v;  // 8 bf16
typedef __attribute__((ext_vector_type(4))) float f32x4;

static __device__ __forceinline__ unsigned short f2bf(float f) {
  unsigned int u = __float_as_uint(f);
  unsigned int r = (u + 0x7fffu + ((u >> 16) & 1u)) >> 16;   // RNE
  return (unsigned short)r;
}
static __device__ __forceinline__ float bf2f(unsigned int bits16) {
  return __uint_as_float(bits16 << 16);
}

// ---------------------------------------------------------------------------
// Kernel A: projections. grid (512, 3), 256 thr, 4 rows/block.
// job 0: UT = (user@Wu)^T ; job 1: AT = (ant@Wa)^T ; job 2: ubase = user@Wres
// ---------------------------------------------------------------------------
__global__ __launch_bounds__(256) void prep_kernel(
    const float* __restrict__ user, const float* __restrict__ ant,
    const float* __restrict__ Wu, const float* __restrict__ Wa,
    const float* __restrict__ Wres, float* __restrict__ ws)
{
  const int job = blockIdx.y;
  const int r0  = blockIdx.x * 4;          // global row in [0, 2048)
  const int b   = r0 >> 8, lr = r0 & 255;  // batch, local row
  const int t   = threadIdx.x;

  const float* X = (job == 1) ? ant : user;
  const float* W = (job == 0) ? Wu : (job == 1) ? Wa : Wres;

  __shared__ float xs[4][UD];
  #pragma unroll
  for (int i = 0; i < 2; ++i) {
    int idx = i * 256 + t;
    xs[idx >> 7][idx & 127] = X[(size_t)(r0 + (idx >> 7)) * UD + (idx & 127)];
  }
  __syncthreads();

  const int j0 = 2 * t;
  const float* wp;
  int wstride;
  if (job < 2) { wp = W + (size_t)(j0 >> 6) * (UD * HD) + (j0 & 63); wstride = HD; }
  else         { wp = W + j0;                                        wstride = HID; }

  float2 acc[4];
  #pragma unroll
  for (int r = 0; r < 4; ++r) acc[r] = make_float2(0.f, 0.f);

  for (int k = 0; k < UD; ++k) {
    float2 w = *(const float2*)(wp + (size_t)k * wstride);
    #pragma unroll
    for (int r = 0; r < 4; ++r) {
      float x = xs[r][k];
      acc[r].x += x * w.x;
      acc[r].y += x * w.y;
    }
  }

  if (job < 2) {
    float* T = ws + (job == 0 ? WS_UT : WS_AT);
    float4 w0 = make_float4(acc[0].x, acc[1].x, acc[2].x, acc[3].x);
    float4 w1 = make_float4(acc[0].y, acc[1].y, acc[2].y, acc[3].y);
    *(float4*)(T + ((size_t)b * HID + j0)     * 256 + lr) = w0;
    *(float4*)(T + ((size_t)b * HID + j0 + 1) * 256 + lr) = w1;
  } else {
    float* outp = ws + WS_UBASE;
    #pragma unroll
    for (int r = 0; r < 4; ++r)
      *(float2*)(outp + (size_t)(r0 + r) * HID + j0) = acc[r];
  }
}

// ---------------------------------------------------------------------------
// Kernel B: per (b,u). Edge staged ONCE as bf16 swizzled LDS; MFMA scores
// with U+A folded into acc-init (float4 from AT); softmax; vectorized accum.
// 256 threads = 4 waves; wave w owns cols [128w, 128w+128).
// ---------------------------------------------------------------------------
__global__ __launch_bounds__(256) void score_user_kernel(
    const float* __restrict__ edge, const float* __restrict__ We,
    const float* __restrict__ av, float* __restrict__ ws,
    float* __restrict__ out)
{
  const int bid = blockIdx.x;          // b*NU + u
  const int b = bid >> 8, u = bid & 255;
  const int t = threadIdx.x;

  __shared__ __align__(16) short ebuf[NA * ED];   // 32 KB bf16, XOR-swizzled
  __shared__ float sc[NA * 9];                    // [a][h] (pad 9)
  __shared__ float gu[H * ED];

  const float* UT = ws + WS_UT;
  const float* AT = ws + WS_AT;

  // ---- stage full edge slice -> bf16 swizzled LDS ----
  {
    const float4* ep = (const float4*)(edge + (size_t)bid * NA * ED);
    #pragma unroll
    for (int i = 0; i < 16; ++i) {
      int s = i * 256 + t;                // float4 slot: 256 rows x 16
      int row = s >> 4, c4 = s & 15;
      float4 v = ep[s];
      ushort4 bv = make_ushort4(f2bf(v.x), f2bf(v.y), f2bf(v.z), f2bf(v.w));
      int byte = row * 128 + c4 * 8;
      byte ^= (row & 7) << 4;
      *(ushort4*)((char*)ebuf + byte) = bv;
    }
  }

  // ---- hoist We frags (bf16), U cols, av ----
  const int w    = t >> 6;
  const int lane = t & 63;
  const int l16  = lane & 15;
  const int kgrp = lane >> 4;

  short8v wf[8][2];
  float   ucol[8];
  float   avv[8];
  #pragma unroll
  for (int n = 0; n < 8; ++n) {
    const int j = 128 * w + 16 * n + l16;
    const int hh = j >> 6, d = j & 63;
    const float* wp = We + (size_t)hh * (ED * HD) + d;
    #pragma unroll
    for (int c = 0; c < 2; ++c) {
      #pragma unroll
      for (int i = 0; i < 8; ++i)
        wf[n][c][i] = (short)f2bf(wp[(size_t)(c * 32 + kgrp * 8 + i) * HD]);
    }
    ucol[n] = UT[((size_t)b * HID + j) * 256 + u];
    avv[n]  = av[hh * HD + d];
  }
  __syncthreads();

  // ---- phase 1: MFMA scores over 8 a-tiles, no barriers ----
  for (int a0 = 0; a0 < NA; a0 += 32) {
    // acc init = U + A (float4 over the q-axis of the C fragment)
    f32x4 acc[2][8];
    const float* ATq = AT + (size_t)b * HID * 256 + a0 + kgrp * 4;
    #pragma unroll
    for (int m = 0; m < 2; ++m) {
      #pragma unroll
      for (int n = 0; n < 8; ++n) {
        const int j = 128 * w + 16 * n + l16;
        float4 a4 = *(const float4*)(ATq + (size_t)j * 256 + m * 16);
        f32x4 v;
        v[0] = a4.x + ucol[n]; v[1] = a4.y + ucol[n];
        v[2] = a4.z + ucol[n]; v[3] = a4.w + ucol[n];
        acc[m][n] = v;
      }
    }

    // A-frags from LDS
    short8v af[2][2];
    #pragma unroll
    for (int m = 0; m < 2; ++m) {
      #pragma unroll
      for (int c = 0; c < 2; ++c) {
        int row = a0 + m * 16 + l16;
        int byte = row * 128 + (c * 32 + kgrp * 8) * 2;
        byte ^= (row & 7) << 4;
        af[m][c] = *(const short8v*)((const char*)ebuf + byte);
      }
    }

    #pragma unroll
    for (int c = 0; c < 2; ++c)
      #pragma unroll
      for (int m = 0; m < 2; ++m)
        #pragma unroll
        for (int n = 0; n < 8; ++n)
          acc[m][n] = __builtin_amdgcn_mfma_f32_16x16x32_bf16(
              af[m][c], wf[n][c], acc[m][n], 0, 0, 0);

    // epilogue: leaky, av-dot, 16-lane reduce (no global loads)
    #pragma unroll
    for (int m = 0; m < 2; ++m) {
      #pragma unroll
      for (int q = 0; q < 4; ++q) {
        const int a_loc = m * 16 + kgrp * 4 + q;
        float h0 = 0.f, h1 = 0.f;
        #pragma unroll
        for (int n = 0; n < 8; ++n) {
          float s = acc[m][n][q];
          s = (s >= 0.f) ? s : SLOPE * s;
          float v = s * avv[n];
          if (n < 4) h0 += v; else h1 += v;
        }
        #pragma unroll
        for (int off = 8; off >= 1; off >>= 1) {
          h0 += __shfl_xor(h0, off);
          h1 += __shfl_xor(h1, off);
        }
        if (l16 == 0) sc[(a0 + a_loc) * 9 + 2 * w]     = h0 * SCALE;
        if (l16 == 1) sc[(a0 + a_loc) * 9 + 2 * w + 1] = h1 * SCALE;
      }
    }
  }
  __syncthreads();

  // ---- phase 2: softmax per head ----
  const int h = t >> 5, l = t & 31;
  {
    float vals[8];
    float m = -1e30f;
    #pragma unroll
    for (int i = 0; i < 8; ++i) {
      vals[i] = sc[(l * 8 + i) * 9 + h];
      m = fmaxf(m, vals[i]);
    }
    #pragma unroll
    for (int off = 16; off >= 1; off >>= 1) m = fmaxf(m, __shfl_xor(m, off));
    float sum = 0.f;
    #pragma unroll
    for (int i = 0; i < 8; ++i) { vals[i] = __expf(vals[i] - m); sum += vals[i]; }
    #pragma unroll
    for (int off = 16; off >= 1; off >>= 1) sum += __shfl_xor(sum, off);
    float inv = 1.0f / sum;
    #pragma unroll
    for (int i = 0; i < 8; ++i) sc[(l * 8 + i) * 9 + h] = vals[i] * inv;
  }
  __syncthreads();

  // ---- phase 3: alpha -> ws [b][a][u][h] ----
  {
    float* ag = ws + WS_ALPHA;
    #pragma unroll
    for (int i = 0; i < 8; ++i) {
      int idx = i * 256 + t;
      int a = idx >> 3, hh = idx & 7;
      ag[(((size_t)b * NA + a) * NU + u) * H + hh] = sc[a * 9 + hh];
    }
  }

  // ---- phase 4: vectorized accumulation ----
  const int j0 = h * HD + 2 * l;
  float g0 = 0.f, g1 = 0.f, pa0 = 0.f, pa1 = 0.f;
  const float* AT0 = AT + ((size_t)b * HID + j0) * 256;
  const float* AT1 = AT0 + 256;
  for (int a0 = 0; a0 < NA; a0 += 8) {
    float p[8];
    #pragma unroll
    for (int i = 0; i < 8; ++i) p[i] = sc[(a0 + i) * 9 + h];
    #pragma unroll
    for (int i2 = 0; i2 < 2; ++i2) {
      float4 A0 = *(const float4*)(AT0 + a0 + i2 * 4);
      float4 A1 = *(const float4*)(AT1 + a0 + i2 * 4);
      pa0 += p[i2*4+0]*A0.x + p[i2*4+1]*A0.y + p[i2*4+2]*A0.z + p[i2*4+3]*A0.w;
      pa1 += p[i2*4+0]*A1.x + p[i2*4+1]*A1.y + p[i2*4+2]*A1.z + p[i2*4+3]*A1.w;
    }
    #pragma unroll
    for (int i = 0; i < 8; ++i) {
      int row = a0 + i;
      int byte = row * 128 + l * 4;
      byte ^= (row & 7) << 4;
      unsigned int uv = *(const unsigned int*)((const char*)ebuf + byte);
      g0 += p[i] * bf2f(uv & 0xffffu);
      g1 += p[i] * bf2f(uv >> 16);
    }
  }
  gu[h * ED + 2 * l]     = g0;
  gu[h * ED + 2 * l + 1] = g1;
  __syncthreads();

  // ---- phase 5: project gu by We, add bases ----
  {
    float o0 = pa0, o1 = pa1;
    const float* wp = We + (size_t)h * (ED * HD) + 2 * l;
    #pragma unroll
    for (int e = 0; e < ED; ++e) {
      float gv = gu[h * ED + e];
      float2 wv = *(const float2*)(wp + (size_t)e * HD);
      o0 += gv * wv.x;
      o1 += gv * wv.y;
    }
    float2 ub = *(const float2*)(ws + WS_UBASE + (size_t)bid * HID + j0);
    *(float2*)(out + (size_t)bid * HID + j0) = make_float2(o0 + ub.x, o1 + ub.y);
  }
}

// ---------------------------------------------------------------------------
// Kernel C: per (b,a): ant_out = sum_u alpha*(U + E). UT float4 streams.
// ---------------------------------------------------------------------------
__global__ __launch_bounds__(256) void ant_kernel(
    const float* __restrict__ edge, const float* __restrict__ We,
    const float* __restrict__ ws, float* __restrict__ out)
{
  const int bid = blockIdx.x;          // b*NA + a
  const int b = bid >> 8, a = bid & 255;
  const int t = threadIdx.x;
  const int h = t >> 5, l = t & 31;
  const int j0 = h * HD + 2 * l;

  __shared__ float elds[32 * ED];
  __shared__ float plds[32 * H];
  __shared__ float ga[H * ED];

  const float* UT0 = ws + WS_UT + ((size_t)b * HID + j0) * 256;
  const float* UT1 = UT0 + 256;
  const float* ag = ws + WS_ALPHA + ((size_t)b * NA + a) * NU * H;

  float g0 = 0.f, g1 = 0.f, pu0 = 0.f, pu1 = 0.f;

  for (int u0 = 0; u0 < NU; u0 += 32) {
    __syncthreads();
    plds[t] = ag[(size_t)u0 * H + t];
    #pragma unroll
    for (int i = 0; i < 2; ++i) {
      int idx = i * 256 + t;
      int uu = idx >> 4, e4 = idx & 15;
      ((float4*)elds)[idx] =
          *(const float4*)(edge + (((size_t)b * NU + u0 + uu) * NA + a) * ED + e4 * 4);
    }
    __syncthreads();

    for (int uu = 0; uu < 32; uu += 4) {
      float4 U0 = *(const float4*)(UT0 + u0 + uu);
      float4 U1 = *(const float4*)(UT1 + u0 + uu);
      float p0 = plds[(uu + 0) * H + h];
      float p1 = plds[(uu + 1) * H + h];
      float p2 = plds[(uu + 2) * H + h];
      float p3 = plds[(uu + 3) * H + h];
      float2 e0 = *(const float2*)(elds + (uu + 0) * ED + 2 * l);
      float2 e1 = *(const float2*)(elds + (uu + 1) * ED + 2 * l);
      float2 e2 = *(const float2*)(elds + (uu + 2) * ED + 2 * l);
      float2 e3 = *(const float2*)(elds + (uu + 3) * ED + 2 * l);
      g0 += p0 * e0.x + p1 * e1.x + p2 * e2.x + p3 * e3.x;
      g1 += p0 * e0.y + p1 * e1.y + p2 * e2.y + p3 * e3.y;
      pu0 += p0 * U0.x + p1 * U0.y + p2 * U0.z + p3 * U0.w;
      pu1 += p0 * U1.x + p1 * U1.y + p2 * U1.z + p3 * U1.w;
    }
  }

  ga[h * ED + 2 * l]     = g0;
  ga[h * ED + 2 * l + 1] = g1;
  __syncthreads();

  float o0 = pu0, o1 = pu1;
  const float* wp = We + (size_t)h * (ED * HD) + 2 * l;
  #pragma unroll
  for (int e = 0; e < ED; ++e) {
    float gv = ga[h * ED + e];
    float2 wv = *(const float2*)(wp + (size_t)e * HD);
    o0 += gv * wv.x;
    o1 += gv * wv.y;
  }
  *(float2*)(out + (size_t)(B_ * NU) * HID + (size_t)bid * HID + j0) =
      make_float2(o0, o1);
}

// ---------------------------------------------------------------------------
extern "C" void kernel_launch(void* const* d_in, const int* in_sizes, int n_in,
                              void* d_out, int out_size, void* d_ws, size_t ws_size,
                              hipStream_t stream) {
  const float* user = (const float*)d_in[0];
  const float* ant  = (const float*)d_in[1];
  const float* edge = (const float*)d_in[2];
  const float* Wu   = (const float*)d_in[3];
  const float* Wa   = (const float*)d_in[4];
  const float* We   = (const float*)d_in[5];
  const float* av   = (const float*)d_in[6];
  const float* Wres = (const float*)d_in[7];
  float* out = (float*)d_out;
  float* ws  = (float*)d_ws;

  prep_kernel<<<dim3(512, 3), 256, 0, stream>>>(user, ant, Wu, Wa, Wres, ws);
  score_user_kernel<<<dim3(B_ * NU), 256, 0, stream>>>(edge, We, av, ws, out);
  ant_kernel<<<dim3(B_ * NA), 256, 0, stream>>>(edge, We, ws, out);
}

// Round 4
// 499.910 us; speedup vs baseline: 1.9635x; 1.3253x over previous
//
#include <hip/hip_runtime.h>
#include <math.h>

// Problem constants
constexpr int B_  = 8;
constexpr int NU  = 256;
constexpr int NA  = 256;
constexpr int UD  = 128;
constexpr int ED  = 64;
constexpr int H   = 8;
constexpr int HD  = 64;
constexpr int HID = 512;
constexpr float SLOPE = 0.2f;
constexpr float SCALE = 0.125f;

// ws layout (floats)
constexpr size_t WS_UT    = 0;          // [B][512][256]  (user@Wu)^T : UT[b][j][u]
constexpr size_t WS_AT    = 1048576;    // [B][512][256]  (ant@Wa)^T  : AT[b][j][a]
constexpr size_t WS_UBASE = 2097152;    // [B][NU][512]   user@Wres
constexpr size_t WS_ALPHA = 3145728;    // [B][NA][NU][H] softmax weights
constexpr size_t WS_WET32 = 7340032;    // [512][64] fp32  WeT[j][e] = We[j>>6][e][j&63]
constexpr size_t WS_WET16 = 7372800;    // [512][64] bf16 (as ushort), same layout

typedef __attribute__((ext_vector_type(8))) short short8v;  // 8 bf16
typedef __attribute__((ext_vector_type(4))) float f32x4;

static __device__ __forceinline__ unsigned short f2bf(float f) {
  unsigned int u = __float_as_uint(f);
  unsigned int r = (u + 0x7fffu + ((u >> 16) & 1u)) >> 16;   // RNE
  return (unsigned short)r;
}
static __device__ __forceinline__ float bf2f(unsigned int bits16) {
  return __uint_as_float(bits16 << 16);
}

// ---------------------------------------------------------------------------
// Kernel A: projections. grid (512, 3), 256 thr, 4 rows/block.
// job 0: UT = (user@Wu)^T ; job 1: AT = (ant@Wa)^T ; job 2: ubase = user@Wres
// ---------------------------------------------------------------------------
__global__ __launch_bounds__(256) void prep_kernel(
    const float* __restrict__ user, const float* __restrict__ ant,
    const float* __restrict__ Wu, const float* __restrict__ Wa,
    const float* __restrict__ Wres, float* __restrict__ ws)
{
  const int job = blockIdx.y;
  const int r0  = blockIdx.x * 4;
  const int b   = r0 >> 8, lr = r0 & 255;
  const int t   = threadIdx.x;

  const float* X = (job == 1) ? ant : user;
  const float* W = (job == 0) ? Wu : (job == 1) ? Wa : Wres;

  __shared__ float xs[4][UD];
  #pragma unroll
  for (int i = 0; i < 2; ++i) {
    int idx = i * 256 + t;
    xs[idx >> 7][idx & 127] = X[(size_t)(r0 + (idx >> 7)) * UD + (idx & 127)];
  }
  __syncthreads();

  const int j0 = 2 * t;
  const float* wp;
  int wstride;
  if (job < 2) { wp = W + (size_t)(j0 >> 6) * (UD * HD) + (j0 & 63); wstride = HD; }
  else         { wp = W + j0;                                        wstride = HID; }

  float2 acc[4];
  #pragma unroll
  for (int r = 0; r < 4; ++r) acc[r] = make_float2(0.f, 0.f);

  for (int k = 0; k < UD; ++k) {
    float2 w = *(const float2*)(wp + (size_t)k * wstride);
    #pragma unroll
    for (int r = 0; r < 4; ++r) {
      float x = xs[r][k];
      acc[r].x += x * w.x;
      acc[r].y += x * w.y;
    }
  }

  if (job < 2) {
    float* T = ws + (job == 0 ? WS_UT : WS_AT);
    float4 w0 = make_float4(acc[0].x, acc[1].x, acc[2].x, acc[3].x);
    float4 w1 = make_float4(acc[0].y, acc[1].y, acc[2].y, acc[3].y);
    *(float4*)(T + ((size_t)b * HID + j0)     * 256 + lr) = w0;
    *(float4*)(T + ((size_t)b * HID + j0 + 1) * 256 + lr) = w1;
  } else {
    float* outp = ws + WS_UBASE;
    #pragma unroll
    for (int r = 0; r < 4; ++r)
      *(float2*)(outp + (size_t)(r0 + r) * HID + j0) = acc[r];
  }
}

// ---------------------------------------------------------------------------
// Kernel A2: WeT precompute. 8 blocks (one per head), 256 threads.
// WeT[j][e] = We[j>>6][e][j&63], fp32 + bf16 copies.
// ---------------------------------------------------------------------------
__global__ __launch_bounds__(256) void weprep_kernel(
    const float* __restrict__ We, float* __restrict__ ws)
{
  const int h = blockIdx.x;
  const int t = threadIdx.x;
  __shared__ float lds[ED * HD];   // We[h] : [e][d]

  const float4* src = (const float4*)(We + (size_t)h * ED * HD);
  #pragma unroll
  for (int i = 0; i < 4; ++i) ((float4*)lds)[i * 256 + t] = src[i * 256 + t];
  __syncthreads();

  const int d = t >> 2, q = t & 3;
  float* WeTf = ws + WS_WET32;
  unsigned short* WeT16 = (unsigned short*)(ws + WS_WET16);
  const size_t jrow = (size_t)(h * HD + d) * ED;
  #pragma unroll
  for (int k = 0; k < 16; ++k) {
    const int e = q * 16 + k;
    float v = lds[e * HD + d];
    WeTf[jrow + e]  = v;
    WeT16[jrow + e] = f2bf(v);
  }
}

// ---------------------------------------------------------------------------
// Kernel B: per (b,u). 512 threads = 8 waves; wave w = head w (64 cols).
// ---------------------------------------------------------------------------
__global__ __launch_bounds__(512, 4) void score_user_kernel(
    const float* __restrict__ edge, const float* __restrict__ av,
    float* __restrict__ ws, float* __restrict__ out)
{
  const int bid = blockIdx.x;          // b*NU + u
  const int b = bid >> 8, u = bid & 255;
  const int t = threadIdx.x;

  __shared__ __align__(16) short ebuf[NA * ED];   // 32 KB bf16, XOR-swizzled
  __shared__ float sc[NA * 9];                    // [a][h] (pad 9)
  __shared__ float gu[HID];                       // [h][e]

  const float* UT = ws + WS_UT;
  const float* AT = ws + WS_AT;

  // ---- stage full edge slice -> bf16 swizzled LDS ----
  {
    const float4* ep = (const float4*)(edge + (size_t)bid * NA * ED);
    #pragma unroll
    for (int i = 0; i < 8; ++i) {
      int s = i * 512 + t;                // float4 slot: 256 rows x 16
      int row = s >> 4, c4 = s & 15;
      float4 v = ep[s];
      ushort4 bv = make_ushort4(f2bf(v.x), f2bf(v.y), f2bf(v.z), f2bf(v.w));
      int byte = row * 128 + c4 * 8;
      byte ^= (row & 7) << 4;
      *(ushort4*)((char*)ebuf + byte) = bv;
    }
  }

  // ---- hoist We frags (contiguous 16B from WeT16), U cols, av ----
  const int w    = t >> 6;          // wave = head
  const int lane = t & 63;
  const int l16  = lane & 15;
  const int kgrp = lane >> 4;

  short8v wf[4][2];
  float   ucol[4];
  float   avv[4];
  const unsigned short* WeT16 = (const unsigned short*)(ws + WS_WET16);
  #pragma unroll
  for (int n = 0; n < 4; ++n) {
    const int j = 64 * w + 16 * n + l16;
    #pragma unroll
    for (int c = 0; c < 2; ++c)
      wf[n][c] = *(const short8v*)(WeT16 + (size_t)j * ED + c * 32 + kgrp * 8);
    ucol[n] = UT[((size_t)b * HID + j) * 256 + u];
    avv[n]  = av[j];
  }
  __syncthreads();

  // ---- phase 1: MFMA scores over 8 a-tiles ----
  for (int a0 = 0; a0 < NA; a0 += 32) {
    f32x4 acc[2][4];
    const float* ATq = AT + (size_t)b * HID * 256 + a0 + kgrp * 4;
    #pragma unroll
    for (int m = 0; m < 2; ++m) {
      #pragma unroll
      for (int n = 0; n < 4; ++n) {
        const int j = 64 * w + 16 * n + l16;
        float4 a4 = *(const float4*)(ATq + (size_t)j * 256 + m * 16);
        f32x4 v;
        v[0] = a4.x + ucol[n]; v[1] = a4.y + ucol[n];
        v[2] = a4.z + ucol[n]; v[3] = a4.w + ucol[n];
        acc[m][n] = v;
      }
    }

    short8v af[2][2];
    #pragma unroll
    for (int m = 0; m < 2; ++m) {
      #pragma unroll
      for (int c = 0; c < 2; ++c) {
        int row = a0 + m * 16 + l16;
        int byte = row * 128 + (c * 32 + kgrp * 8) * 2;
        byte ^= (row & 7) << 4;
        af[m][c] = *(const short8v*)((const char*)ebuf + byte);
      }
    }

    #pragma unroll
    for (int c = 0; c < 2; ++c)
      #pragma unroll
      for (int m = 0; m < 2; ++m)
        #pragma unroll
        for (int n = 0; n < 4; ++n)
          acc[m][n] = __builtin_amdgcn_mfma_f32_16x16x32_bf16(
              af[m][c], wf[n][c], acc[m][n], 0, 0, 0);

    // epilogue: leaky, av-dot, 16-lane reduce -> sc[a][w]
    #pragma unroll
    for (int m = 0; m < 2; ++m) {
      #pragma unroll
      for (int q = 0; q < 4; ++q) {
        const int a_loc = m * 16 + kgrp * 4 + q;
        float h0 = 0.f;
        #pragma unroll
        for (int n = 0; n < 4; ++n) {
          float s = acc[m][n][q];
          s = (s >= 0.f) ? s : SLOPE * s;
          h0 += s * avv[n];
        }
        #pragma unroll
        for (int off = 8; off >= 1; off >>= 1) h0 += __shfl_xor(h0, off);
        if (l16 == 0) sc[(a0 + a_loc) * 9 + w] = h0 * SCALE;
      }
    }
  }
  __syncthreads();

  // ---- phase 2: softmax per head (wave = head, 64 lanes, 4 vals each) ----
  {
    float vals[4];
    float m = -1e30f;
    #pragma unroll
    for (int i = 0; i < 4; ++i) {
      vals[i] = sc[(lane * 4 + i) * 9 + w];
      m = fmaxf(m, vals[i]);
    }
    #pragma unroll
    for (int off = 32; off >= 1; off >>= 1) m = fmaxf(m, __shfl_xor(m, off));
    float sum = 0.f;
    #pragma unroll
    for (int i = 0; i < 4; ++i) { vals[i] = __expf(vals[i] - m); sum += vals[i]; }
    #pragma unroll
    for (int off = 32; off >= 1; off >>= 1) sum += __shfl_xor(sum, off);
    float inv = 1.0f / sum;
    #pragma unroll
    for (int i = 0; i < 4; ++i) sc[(lane * 4 + i) * 9 + w] = vals[i] * inv;
  }
  __syncthreads();

  // ---- phase 3: alpha -> ws [b][a][u][h] ----
  {
    float* ag = ws + WS_ALPHA;
    #pragma unroll
    for (int i = 0; i < 4; ++i) {
      int idx = i * 512 + t;
      int a = idx >> 3, hh = idx & 7;
      ag[(((size_t)b * NA + a) * NU + u) * H + hh] = sc[a * 9 + hh];
    }
  }

  // ---- phase 4: thread t = col j; (h,e) = (t>>6, t&63) ----
  float g = 0.f, pa = 0.f;
  const float* ATj = AT + ((size_t)b * HID + t) * 256;
  for (int a0 = 0; a0 < NA; a0 += 8) {
    float p[8];
    #pragma unroll
    for (int i = 0; i < 8; ++i) p[i] = sc[(a0 + i) * 9 + w];
    float4 A0 = *(const float4*)(ATj + a0);
    float4 A1 = *(const float4*)(ATj + a0 + 4);
    pa += p[0]*A0.x + p[1]*A0.y + p[2]*A0.z + p[3]*A0.w
        + p[4]*A1.x + p[5]*A1.y + p[6]*A1.z + p[7]*A1.w;
    #pragma unroll
    for (int i = 0; i < 8; ++i) {
      int row = a0 + i;
      int byte = row * 128 + lane * 2;
      byte ^= (row & 7) << 4;
      g += p[i] * bf2f(*(const unsigned short*)((const char*)ebuf + byte));
    }
  }
  gu[t] = g;
  __syncthreads();

  // ---- phase 5: project gu by WeT fp32 (contiguous row), add bases ----
  {
    float o = pa;
    const float* wrow = ws + WS_WET32 + (size_t)t * ED;
    const float* gur  = gu + w * ED;
    #pragma unroll
    for (int e0 = 0; e0 < ED; e0 += 4) {
      float4 wv = *(const float4*)(wrow + e0);
      o += gur[e0]*wv.x + gur[e0+1]*wv.y + gur[e0+2]*wv.z + gur[e0+3]*wv.w;
    }
    o += ws[WS_UBASE + (size_t)bid * HID + t];
    out[(size_t)bid * HID + t] = o;
  }
}

// ---------------------------------------------------------------------------
// Kernel C: per (b,a). 512 threads; thread t = out col j; (h,e)=(t>>6,t&63).
// ---------------------------------------------------------------------------
__global__ __launch_bounds__(512, 4) void ant_kernel(
    const float* __restrict__ edge, const float* __restrict__ ws,
    float* __restrict__ out)
{
  const int bid = blockIdx.x;          // b*NA + a
  const int b = bid >> 8, a = bid & 255;
  const int t = threadIdx.x;
  const int h = t >> 6, e = t & 63;

  __shared__ float elds[32 * ED];   // 8 KB
  __shared__ float plds[32 * H];    // 1 KB
  __shared__ float ga[HID];

  const float* UTj = ws + WS_UT + ((size_t)b * HID + t) * 256;
  const float* ag  = ws + WS_ALPHA + ((size_t)b * NA + a) * NU * H;

  float g = 0.f, pu = 0.f;

  for (int u0 = 0; u0 < NU; u0 += 32) {
    __syncthreads();
    if (t < 256) plds[t] = ag[(size_t)u0 * H + t];
    {
      int uu = t >> 4, e4 = t & 15;
      ((float4*)elds)[t] =
          *(const float4*)(edge + (((size_t)b * NU + u0 + uu) * NA + a) * ED + e4 * 4);
    }
    __syncthreads();

    #pragma unroll
    for (int u4 = 0; u4 < 8; ++u4) {
      float4 U = *(const float4*)(UTj + u0 + u4 * 4);
      float p0 = plds[(u4 * 4 + 0) * H + h];
      float p1 = plds[(u4 * 4 + 1) * H + h];
      float p2 = plds[(u4 * 4 + 2) * H + h];
      float p3 = plds[(u4 * 4 + 3) * H + h];
      g += p0 * elds[(u4 * 4 + 0) * ED + e] + p1 * elds[(u4 * 4 + 1) * ED + e]
         + p2 * elds[(u4 * 4 + 2) * ED + e] + p3 * elds[(u4 * 4 + 3) * ED + e];
      pu += p0 * U.x + p1 * U.y + p2 * U.z + p3 * U.w;
    }
  }

  ga[t] = g;
  __syncthreads();

  float o = pu;
  const float* wrow = ws + WS_WET32 + (size_t)t * ED;
  const float* gar  = ga + h * ED;
  #pragma unroll
  for (int e0 = 0; e0 < ED; e0 += 4) {
    float4 wv = *(const float4*)(wrow + e0);
    o += gar[e0]*wv.x + gar[e0+1]*wv.y + gar[e0+2]*wv.z + gar[e0+3]*wv.w;
  }
  out[(size_t)(B_ * NU) * HID + (size_t)bid * HID + t] = o;
}

// ---------------------------------------------------------------------------
extern "C" void kernel_launch(void* const* d_in, const int* in_sizes, int n_in,
                              void* d_out, int out_size, void* d_ws, size_t ws_size,
                              hipStream_t stream) {
  const float* user = (const float*)d_in[0];
  const float* ant  = (const float*)d_in[1];
  const float* edge = (const float*)d_in[2];
  const float* Wu   = (const float*)d_in[3];
  const float* Wa   = (const float*)d_in[4];
  const float* We   = (const float*)d_in[5];
  const float* av   = (const float*)d_in[6];
  const float* Wres = (const float*)d_in[7];
  float* out = (float*)d_out;
  float* ws  = (float*)d_ws;

  prep_kernel<<<dim3(512, 3), 256, 0, stream>>>(user, ant, Wu, Wa, Wres, ws);
  weprep_kernel<<<dim3(8), 256, 0, stream>>>(We, ws);
  score_user_kernel<<<dim3(B_ * NU), 512, 0, stream>>>(edge, av, ws, out);
  ant_kernel<<<dim3(B_ * NA), 512, 0, stream>>>(edge, ws, out);
}

// Round 5
// 389.790 us; speedup vs baseline: 2.5181x; 1.2825x over previous
//
#include <hip/hip_runtime.h>
#include <math.h>

// Problem constants
constexpr int B_  = 8;
constexpr int NU  = 256;
constexpr int NA  = 256;
constexpr int UD  = 128;
constexpr int ED  = 64;
constexpr int H   = 8;
constexpr int HD  = 64;
constexpr int HID = 512;
constexpr float SLOPE = 0.2f;
constexpr float SCALE = 0.125f;

// ws layout (floats)
constexpr size_t WS_UT    = 0;          // [B][512][256]  (user@Wu)^T : UT[b][j][u]
constexpr size_t WS_AT    = 1048576;    // [B][512][256]  (ant@Wa)^T  : AT[b][j][a]
constexpr size_t WS_UBASE = 2097152;    // [B][NU][512]   user@Wres
constexpr size_t WS_ALPHA = 3145728;    // [B][NA][NU][H] softmax weights
constexpr size_t WS_WET32 = 7340032;    // [512][64] fp32  WeT[j][e] = We[j>>6][e][j&63]
constexpr size_t WS_WET16 = 7372800;    // [512][64] bf16 (as ushort), same layout

typedef __attribute__((ext_vector_type(8))) short short8v;  // 8 bf16
typedef __attribute__((ext_vector_type(4))) float f32x4;

static __device__ __forceinline__ unsigned short f2bf(float f) {
  unsigned int u = __float_as_uint(f);
  unsigned int r = (u + 0x7fffu + ((u >> 16) & 1u)) >> 16;   // RNE
  return (unsigned short)r;
}

// ---------------------------------------------------------------------------
// Kernel A: projections. grid (512, 3), 256 thr, 4 rows/block.
// job 0: UT = (user@Wu)^T ; job 1: AT = (ant@Wa)^T ; job 2: ubase = user@Wres
// ---------------------------------------------------------------------------
__global__ __launch_bounds__(256) void prep_kernel(
    const float* __restrict__ user, const float* __restrict__ ant,
    const float* __restrict__ Wu, const float* __restrict__ Wa,
    const float* __restrict__ Wres, float* __restrict__ ws)
{
  const int job = blockIdx.y;
  const int r0  = blockIdx.x * 4;
  const int b   = r0 >> 8, lr = r0 & 255;
  const int t   = threadIdx.x;

  const float* X = (job == 1) ? ant : user;
  const float* W = (job == 0) ? Wu : (job == 1) ? Wa : Wres;

  __shared__ float xs[4][UD];
  #pragma unroll
  for (int i = 0; i < 2; ++i) {
    int idx = i * 256 + t;
    xs[idx >> 7][idx & 127] = X[(size_t)(r0 + (idx >> 7)) * UD + (idx & 127)];
  }
  __syncthreads();

  const int j0 = 2 * t;
  const float* wp;
  int wstride;
  if (job < 2) { wp = W + (size_t)(j0 >> 6) * (UD * HD) + (j0 & 63); wstride = HD; }
  else         { wp = W + j0;                                        wstride = HID; }

  float2 acc[4];
  #pragma unroll
  for (int r = 0; r < 4; ++r) acc[r] = make_float2(0.f, 0.f);

  for (int k = 0; k < UD; ++k) {
    float2 w = *(const float2*)(wp + (size_t)k * wstride);
    #pragma unroll
    for (int r = 0; r < 4; ++r) {
      float x = xs[r][k];
      acc[r].x += x * w.x;
      acc[r].y += x * w.y;
    }
  }

  if (job < 2) {
    float* T = ws + (job == 0 ? WS_UT : WS_AT);
    float4 w0 = make_float4(acc[0].x, acc[1].x, acc[2].x, acc[3].x);
    float4 w1 = make_float4(acc[0].y, acc[1].y, acc[2].y, acc[3].y);
    *(float4*)(T + ((size_t)b * HID + j0)     * 256 + lr) = w0;
    *(float4*)(T + ((size_t)b * HID + j0 + 1) * 256 + lr) = w1;
  } else {
    float* outp = ws + WS_UBASE;
    #pragma unroll
    for (int r = 0; r < 4; ++r)
      *(float2*)(outp + (size_t)(r0 + r) * HID + j0) = acc[r];
  }
}

// ---------------------------------------------------------------------------
// Kernel A2: WeT precompute. 8 blocks (one per head), 256 threads.
// ---------------------------------------------------------------------------
__global__ __launch_bounds__(256) void weprep_kernel(
    const float* __restrict__ We, float* __restrict__ ws)
{
  const int h = blockIdx.x;
  const int t = threadIdx.x;
  __shared__ float lds[ED * HD];

  const float4* src = (const float4*)(We + (size_t)h * ED * HD);
  #pragma unroll
  for (int i = 0; i < 4; ++i) ((float4*)lds)[i * 256 + t] = src[i * 256 + t];
  __syncthreads();

  const int d = t >> 2, q = t & 3;
  float* WeTf = ws + WS_WET32;
  unsigned short* WeT16 = (unsigned short*)(ws + WS_WET16);
  const size_t jrow = (size_t)(h * HD + d) * ED;
  #pragma unroll
  for (int k = 0; k < 16; ++k) {
    const int e = q * 16 + k;
    float v = lds[e * HD + d];
    WeTf[jrow + e]  = v;
    WeT16[jrow + e] = f2bf(v);
  }
}

// ---------------------------------------------------------------------------
// Kernel B: per (b,u). 512 threads = 8 waves; wave w = head w.
// Single pass over a-tiles: MFMA scores + online-softmax accumulation of
// O[j] = sum_a alpha*(A+Eproj)[a][j] directly from the MFMA accumulator.
// ---------------------------------------------------------------------------
__global__ __launch_bounds__(512, 4) void score_user_kernel(
    const float* __restrict__ edge, const float* __restrict__ av,
    float* __restrict__ ws, float* __restrict__ out)
{
  const int bid = blockIdx.x;          // b*NU + u
  const int b = bid >> 8, u = bid & 255;
  const int t = threadIdx.x;

  __shared__ __align__(16) short ebuf[2][32 * ED];  // 2 x 4 KB bf16, swizzled
  __shared__ float sc[NA * 9];                      // raw scores -> alpha
  __shared__ float gu[HID];

  const float* UT = ws + WS_UT;
  const float* AT = ws + WS_AT;

  const int w    = t >> 6;          // wave = head
  const int lane = t & 63;
  const int l16  = lane & 15;
  const int kgrp = lane >> 4;

  // hoist We fragments (bf16), U cols, av
  short8v wf[4][2];
  float   ucol[4];
  float   avv[4];
  const unsigned short* WeT16 = (const unsigned short*)(ws + WS_WET16);
  #pragma unroll
  for (int n = 0; n < 4; ++n) {
    const int j = 64 * w + 16 * n + l16;
    #pragma unroll
    for (int c = 0; c < 2; ++c)
      wf[n][c] = *(const short8v*)(WeT16 + (size_t)j * ED + c * 32 + kgrp * 8);
    ucol[n] = UT[((size_t)b * HID + j) * 256 + u];
    avv[n]  = av[j];
  }

  // staging geometry: thread t -> float4 slot (row = t>>4, c4 = t&15)
  const float4* ep = (const float4*)(edge + (size_t)bid * NA * ED);
  const int srow = t >> 4, sc4 = t & 15;
  const int sbyte = (srow * 128 + sc4 * 8) ^ ((srow & 7) << 4);
  float4 v = ep[t];   // tile 0 prefetch

  float M = -INFINITY, lsum = 0.f;
  float O[4] = {0.f, 0.f, 0.f, 0.f};

  for (int t8 = 0; t8 < 8; ++t8) {
    const int cur = t8 & 1;
    {
      ushort4 bv = make_ushort4(f2bf(v.x), f2bf(v.y), f2bf(v.z), f2bf(v.w));
      *(ushort4*)((char*)ebuf[cur] + sbyte) = bv;
    }
    if (t8 < 7) v = ep[(t8 + 1) * 512 + t];   // prefetch next tile
    __syncthreads();                          // tile staged; prev compute done

    const int a0 = t8 * 32;

    // acc init = A (pure loads; U added in epilogue)
    f32x4 acc[2][4];
    const float* ATq = AT + (size_t)b * HID * 256 + a0 + kgrp * 4;
    #pragma unroll
    for (int m = 0; m < 2; ++m) {
      #pragma unroll
      for (int n = 0; n < 4; ++n) {
        const int j = 64 * w + 16 * n + l16;
        float4 a4 = *(const float4*)(ATq + (size_t)j * 256 + m * 16);
        f32x4 vv; vv[0] = a4.x; vv[1] = a4.y; vv[2] = a4.z; vv[3] = a4.w;
        acc[m][n] = vv;
      }
    }

    // A-fragments from LDS
    short8v af[2][2];
    #pragma unroll
    for (int m = 0; m < 2; ++m) {
      #pragma unroll
      for (int c = 0; c < 2; ++c) {
        int row = m * 16 + l16;
        int byte = (row * 128 + (c * 32 + kgrp * 8) * 2) ^ ((row & 7) << 4);
        af[m][c] = *(const short8v*)((const char*)ebuf[cur] + byte);
      }
    }

    #pragma unroll
    for (int c = 0; c < 2; ++c)
      #pragma unroll
      for (int m = 0; m < 2; ++m)
        #pragma unroll
        for (int n = 0; n < 4; ++n)
          acc[m][n] = __builtin_amdgcn_mfma_f32_16x16x32_bf16(
              af[m][c], wf[n][c], acc[m][n], 0, 0, 0);

    // scores: leaky(acc+U) . av, 16-lane butterfly -> s8 (all lanes have them)
    float s8[8];
    #pragma unroll
    for (int m = 0; m < 2; ++m) {
      #pragma unroll
      for (int q = 0; q < 4; ++q) {
        float h0 = 0.f;
        #pragma unroll
        for (int n = 0; n < 4; ++n) {
          float s = acc[m][n][q] + ucol[n];
          s = (s >= 0.f) ? s : SLOPE * s;
          h0 += s * avv[n];
        }
        #pragma unroll
        for (int off = 8; off >= 1; off >>= 1) h0 += __shfl_xor(h0, off);
        h0 *= SCALE;
        s8[m * 4 + q] = h0;
        if (l16 == 0) sc[(a0 + m * 16 + kgrp * 4 + q) * 9 + w] = h0;
      }
    }

    // online softmax update (cross-kgrp reduce deferred to the end)
    float tmax = s8[0];
    #pragma unroll
    for (int r = 1; r < 8; ++r) tmax = fmaxf(tmax, s8[r]);
    tmax = fmaxf(tmax, __shfl_xor(tmax, 16));
    tmax = fmaxf(tmax, __shfl_xor(tmax, 32));
    float Mnew = fmaxf(M, tmax);
    float f = __expf(M - Mnew);
    lsum *= f;
    #pragma unroll
    for (int n = 0; n < 4; ++n) O[n] *= f;
    #pragma unroll
    for (int r = 0; r < 8; ++r) { s8[r] = __expf(s8[r] - Mnew); lsum += s8[r]; }
    #pragma unroll
    for (int m = 0; m < 2; ++m)
      #pragma unroll
      for (int q = 0; q < 4; ++q) {
        float ww = s8[m * 4 + q];
        #pragma unroll
        for (int n = 0; n < 4; ++n) O[n] += ww * acc[m][n][q];
      }
    M = Mnew;
  }

  // final reductions across kgrp
  lsum += __shfl_xor(lsum, 16);
  lsum += __shfl_xor(lsum, 32);
  #pragma unroll
  for (int n = 0; n < 4; ++n) {
    O[n] += __shfl_xor(O[n], 16);
    O[n] += __shfl_xor(O[n], 32);
  }
  const float inv = 1.0f / lsum;

  __syncthreads();

  // alpha = exp(s - M) * inv, written back into sc
  {
    float vals[4];
    #pragma unroll
    for (int i = 0; i < 4; ++i) vals[i] = sc[(lane * 4 + i) * 9 + w];
    #pragma unroll
    for (int i = 0; i < 4; ++i)
      sc[(lane * 4 + i) * 9 + w] = __expf(vals[i] - M) * inv;
  }
  if (kgrp == 0) {
    #pragma unroll
    for (int n = 0; n < 4; ++n) gu[w * 64 + n * 16 + l16] = O[n] * inv;
  }
  __syncthreads();

  // alpha scatter -> ws [b][a][u][h]
  {
    float* ag = ws + WS_ALPHA;
    #pragma unroll
    for (int i = 0; i < 4; ++i) {
      int idx = i * 512 + t;
      int a = idx >> 3, hh = idx & 7;
      ag[(((size_t)b * NA + a) * NU + u) * H + hh] = sc[a * 9 + hh];
    }
  }
  out[(size_t)bid * HID + t] = gu[t] + ws[WS_UBASE + (size_t)bid * HID + t];
}

// ---------------------------------------------------------------------------
// Kernel C: per (b,a). 512 threads; thread t = out col j; (h,e)=(t>>6,t&63).
// No edge LDS: wave-coherent direct global reads; alpha staged once.
// ---------------------------------------------------------------------------
__global__ __launch_bounds__(512, 4) void ant_kernel(
    const float* __restrict__ edge, const float* __restrict__ ws,
    float* __restrict__ out)
{
  const int bid = blockIdx.x;          // b*NA + a
  const int b = bid >> 8, a = bid & 255;
  const int t = threadIdx.x;
  const int h = t >> 6, e = t & 63;

  __shared__ float plds[NU * H];   // 8 KB: alpha[b][a][:][:]
  __shared__ float ga[HID];

  const float* ag = ws + WS_ALPHA + ((size_t)b * NA + a) * NU * H;
  ((float4*)plds)[t] = ((const float4*)ag)[t];
  __syncthreads();

  const float* UTj = ws + WS_UT + ((size_t)b * HID + t) * 256;
  const float* ec  = edge + ((size_t)(b * NU) * NA + a) * ED + e;

  float g = 0.f, pu = 0.f;

  for (int u0 = 0; u0 < NU; u0 += 8) {
    float4 U0 = *(const float4*)(UTj + u0);
    float4 U1 = *(const float4*)(UTj + u0 + 4);
    float p[8], ev[8];
    #pragma unroll
    for (int i = 0; i < 8; ++i) p[i] = plds[(u0 + i) * H + h];
    #pragma unroll
    for (int i = 0; i < 8; ++i) ev[i] = ec[(size_t)(u0 + i) * (NA * ED)];
    #pragma unroll
    for (int i = 0; i < 8; ++i) g += p[i] * ev[i];
    pu += p[0] * U0.x + p[1] * U0.y + p[2] * U0.z + p[3] * U0.w
        + p[4] * U1.x + p[5] * U1.y + p[6] * U1.z + p[7] * U1.w;
  }

  ga[t] = g;
  __syncthreads();

  float o = pu;
  const float* wrow = ws + WS_WET32 + (size_t)t * ED;
  const float* gar  = ga + h * ED;
  #pragma unroll
  for (int e0 = 0; e0 < ED; e0 += 4) {
    float4 wv = *(const float4*)(wrow + e0);
    o += gar[e0]*wv.x + gar[e0+1]*wv.y + gar[e0+2]*wv.z + gar[e0+3]*wv.w;
  }
  out[(size_t)(B_ * NU) * HID + (size_t)bid * HID + t] = o;
}

// ---------------------------------------------------------------------------
extern "C" void kernel_launch(void* const* d_in, const int* in_sizes, int n_in,
                              void* d_out, int out_size, void* d_ws, size_t ws_size,
                              hipStream_t stream) {
  const float* user = (const float*)d_in[0];
  const float* ant  = (const float*)d_in[1];
  const float* edge = (const float*)d_in[2];
  const float* Wu   = (const float*)d_in[3];
  const float* Wa   = (const float*)d_in[4];
  const float* We   = (const float*)d_in[5];
  const float* av   = (const float*)d_in[6];
  const float* Wres = (const float*)d_in[7];
  float* out = (float*)d_out;
  float* ws  = (float*)d_ws;

  prep_kernel<<<dim3(512, 3), 256, 0, stream>>>(user, ant, Wu, Wa, Wres, ws);
  weprep_kernel<<<dim3(8), 256, 0, stream>>>(We, ws);
  score_user_kernel<<<dim3(B_ * NU), 512, 0, stream>>>(edge, av, ws, out);
  ant_kernel<<<dim3(B_ * NA), 512, 0, stream>>>(edge, ws, out);
}

// Round 6
// 365.602 us; speedup vs baseline: 2.6847x; 1.0662x over previous
//
#include <hip/hip_runtime.h>
#include <math.h>

// Problem constants
constexpr int B_  = 8;
constexpr int NU  = 256;
constexpr int NA  = 256;
constexpr int UD  = 128;
constexpr int ED  = 64;
constexpr int H   = 8;
constexpr int HD  = 64;
constexpr int HID = 512;
constexpr float SLOPE = 0.2f;
constexpr float SCALE = 0.125f;

// ws layout (floats)
constexpr size_t WS_UT    = 0;          // [B][512][256]  (user@Wu)^T : UT[b][j][u]
constexpr size_t WS_AT    = 1048576;    // [B][512][256]  (ant@Wa)^T  : AT[b][j][a]
constexpr size_t WS_UBASE = 2097152;    // [B][NU][512]   user@Wres
constexpr size_t WS_ALPHA = 3145728;    // [B][NA][NU][H] softmax weights
constexpr size_t WS_WET32 = 7340032;    // [512][64] fp32  WeT[j][e] = We[j>>6][e][j&63]
constexpr size_t WS_WET16 = 7372800;    // [512][64] bf16 (as ushort), same layout

typedef __attribute__((ext_vector_type(8))) short short8v;  // 8 bf16
typedef __attribute__((ext_vector_type(4))) float f32x4;

static __device__ __forceinline__ unsigned short f2bf(float f) {
  unsigned int u = __float_as_uint(f);
  unsigned int r = (u + 0x7fffu + ((u >> 16) & 1u)) >> 16;   // RNE
  return (unsigned short)r;
}

// ---------------------------------------------------------------------------
// Kernel A: projections. grid (512, 3), 256 thr, 4 rows/block.
// ---------------------------------------------------------------------------
__global__ __launch_bounds__(256) void prep_kernel(
    const float* __restrict__ user, const float* __restrict__ ant,
    const float* __restrict__ Wu, const float* __restrict__ Wa,
    const float* __restrict__ Wres, float* __restrict__ ws)
{
  const int job = blockIdx.y;
  const int r0  = blockIdx.x * 4;
  const int b   = r0 >> 8, lr = r0 & 255;
  const int t   = threadIdx.x;

  const float* X = (job == 1) ? ant : user;
  const float* W = (job == 0) ? Wu : (job == 1) ? Wa : Wres;

  __shared__ float xs[4][UD];
  #pragma unroll
  for (int i = 0; i < 2; ++i) {
    int idx = i * 256 + t;
    xs[idx >> 7][idx & 127] = X[(size_t)(r0 + (idx >> 7)) * UD + (idx & 127)];
  }
  __syncthreads();

  const int j0 = 2 * t;
  const float* wp;
  int wstride;
  if (job < 2) { wp = W + (size_t)(j0 >> 6) * (UD * HD) + (j0 & 63); wstride = HD; }
  else         { wp = W + j0;                                        wstride = HID; }

  float2 acc[4];
  #pragma unroll
  for (int r = 0; r < 4; ++r) acc[r] = make_float2(0.f, 0.f);

  for (int k = 0; k < UD; ++k) {
    float2 w = *(const float2*)(wp + (size_t)k * wstride);
    #pragma unroll
    for (int r = 0; r < 4; ++r) {
      float x = xs[r][k];
      acc[r].x += x * w.x;
      acc[r].y += x * w.y;
    }
  }

  if (job < 2) {
    float* T = ws + (job == 0 ? WS_UT : WS_AT);
    float4 w0 = make_float4(acc[0].x, acc[1].x, acc[2].x, acc[3].x);
    float4 w1 = make_float4(acc[0].y, acc[1].y, acc[2].y, acc[3].y);
    *(float4*)(T + ((size_t)b * HID + j0)     * 256 + lr) = w0;
    *(float4*)(T + ((size_t)b * HID + j0 + 1) * 256 + lr) = w1;
  } else {
    float* outp = ws + WS_UBASE;
    #pragma unroll
    for (int r = 0; r < 4; ++r)
      *(float2*)(outp + (size_t)(r0 + r) * HID + j0) = acc[r];
  }
}

// ---------------------------------------------------------------------------
// Kernel A2: WeT precompute. 8 blocks (one per head), 256 threads.
// ---------------------------------------------------------------------------
__global__ __launch_bounds__(256) void weprep_kernel(
    const float* __restrict__ We, float* __restrict__ ws)
{
  const int h = blockIdx.x;
  const int t = threadIdx.x;
  __shared__ float lds[ED * HD];

  const float4* src = (const float4*)(We + (size_t)h * ED * HD);
  #pragma unroll
  for (int i = 0; i < 4; ++i) ((float4*)lds)[i * 256 + t] = src[i * 256 + t];
  __syncthreads();

  const int d = t >> 2, q = t & 3;
  float* WeTf = ws + WS_WET32;
  unsigned short* WeT16 = (unsigned short*)(ws + WS_WET16);
  const size_t jrow = (size_t)(h * HD + d) * ED;
  #pragma unroll
  for (int k = 0; k < 16; ++k) {
    const int e = q * 16 + k;
    float v = lds[e * HD + d];
    WeTf[jrow + e]  = v;
    WeT16[jrow + e] = f2bf(v);
  }
}

// ---------------------------------------------------------------------------
// Kernel B: per (b,u). 512 threads = 8 waves; wave w = head w.
// MFMA scores + defer-max softmax accumulation; AT register prefetch.
// ---------------------------------------------------------------------------
__global__ __launch_bounds__(512, 4) void score_user_kernel(
    const float* __restrict__ edge, const float* __restrict__ av,
    float* __restrict__ ws, float* __restrict__ out)
{
  const int bid = blockIdx.x;          // b*NU + u
  const int b = bid >> 8, u = bid & 255;
  const int t = threadIdx.x;

  __shared__ __align__(16) short ebuf[2][32 * ED];  // 2 x 4 KB bf16, swizzled
  __shared__ float sc[NA * 9];                      // exp(score) per [a][h]
  __shared__ float gu[HID];
  __shared__ float sinv[H];

  const float* UT = ws + WS_UT;
  const float* AT = ws + WS_AT;

  const int w    = t >> 6;          // wave = head
  const int lane = t & 63;
  const int l16  = lane & 15;
  const int kgrp = lane >> 4;

  // hoist We fragments (bf16), U cols, av
  short8v wf[4][2];
  float   ucol[4];
  float   avv[4];
  const unsigned short* WeT16 = (const unsigned short*)(ws + WS_WET16);
  #pragma unroll
  for (int n = 0; n < 4; ++n) {
    const int j = 64 * w + 16 * n + l16;
    #pragma unroll
    for (int c = 0; c < 2; ++c)
      wf[n][c] = *(const short8v*)(WeT16 + (size_t)j * ED + c * 32 + kgrp * 8);
    ucol[n] = UT[((size_t)b * HID + j) * 256 + u];
    avv[n]  = av[j];
  }

  // staging geometry
  const float4* ep = (const float4*)(edge + (size_t)bid * NA * ED);
  const int srow = t >> 4, sc4 = t & 15;
  const int sbyte = (srow * 128 + sc4 * 8) ^ ((srow & 7) << 4);
  float4 v = ep[t];   // tile 0 edge prefetch

  // AT prefetch (tile 0) into registers
  const float* ATbase = AT + (size_t)b * HID * 256 + kgrp * 4;
  float4 atreg[2][4];
  #pragma unroll
  for (int m = 0; m < 2; ++m)
    #pragma unroll
    for (int n = 0; n < 4; ++n) {
      const int j = 64 * w + 16 * n + l16;
      atreg[m][n] = *(const float4*)(ATbase + (size_t)j * 256 + m * 16);
    }

  float lsum = 0.f;
  float O[4] = {0.f, 0.f, 0.f, 0.f};

  for (int t8 = 0; t8 < 8; ++t8) {
    const int cur = t8 & 1;
    {
      ushort4 bv = make_ushort4(f2bf(v.x), f2bf(v.y), f2bf(v.z), f2bf(v.w));
      *(ushort4*)((char*)ebuf[cur] + sbyte) = bv;
    }
    if (t8 < 7) v = ep[(t8 + 1) * 512 + t];   // edge prefetch next tile
    __syncthreads();

    // consume prefetched AT as acc init
    f32x4 acc[2][4];
    #pragma unroll
    for (int m = 0; m < 2; ++m)
      #pragma unroll
      for (int n = 0; n < 4; ++n) {
        f32x4 vv;
        vv[0] = atreg[m][n].x; vv[1] = atreg[m][n].y;
        vv[2] = atreg[m][n].z; vv[3] = atreg[m][n].w;
        acc[m][n] = vv;
      }

    // issue AT prefetch for next tile (overlaps MFMA + epilogue)
    if (t8 < 7) {
      const int a0n = (t8 + 1) * 32;
      #pragma unroll
      for (int m = 0; m < 2; ++m)
        #pragma unroll
        for (int n = 0; n < 4; ++n) {
          const int j = 64 * w + 16 * n + l16;
          atreg[m][n] = *(const float4*)(ATbase + (size_t)j * 256 + a0n + m * 16);
        }
    }

    // A-fragments from LDS
    short8v af[2][2];
    #pragma unroll
    for (int m = 0; m < 2; ++m) {
      #pragma unroll
      for (int c = 0; c < 2; ++c) {
        int row = m * 16 + l16;
        int byte = (row * 128 + (c * 32 + kgrp * 8) * 2) ^ ((row & 7) << 4);
        af[m][c] = *(const short8v*)((const char*)ebuf[cur] + byte);
      }
    }

    #pragma unroll
    for (int c = 0; c < 2; ++c)
      #pragma unroll
      for (int m = 0; m < 2; ++m)
        #pragma unroll
        for (int n = 0; n < 4; ++n)
          acc[m][n] = __builtin_amdgcn_mfma_f32_16x16x32_bf16(
              af[m][c], wf[n][c], acc[m][n], 0, 0, 0);

    // epilogue: leaky(acc+U).av, butterfly, exp (defer-max), accumulate
    const int a0 = t8 * 32;
    #pragma unroll
    for (int m = 0; m < 2; ++m) {
      #pragma unroll
      for (int q = 0; q < 4; ++q) {
        float h0 = 0.f;
        #pragma unroll
        for (int n = 0; n < 4; ++n) {
          float s = acc[m][n][q] + ucol[n];
          s = (s >= 0.f) ? s : SLOPE * s;
          h0 += s * avv[n];
        }
        #pragma unroll
        for (int off = 8; off >= 1; off >>= 1) h0 += __shfl_xor(h0, off);
        float e = __expf(h0 * SCALE);
        lsum += e;
        if (l16 == 0) sc[(a0 + m * 16 + kgrp * 4 + q) * 9 + w] = e;
        #pragma unroll
        for (int n = 0; n < 4; ++n) O[n] += e * acc[m][n][q];
      }
    }
  }

  // final reductions across kgrp
  lsum += __shfl_xor(lsum, 16);
  lsum += __shfl_xor(lsum, 32);
  #pragma unroll
  for (int n = 0; n < 4; ++n) {
    O[n] += __shfl_xor(O[n], 16);
    O[n] += __shfl_xor(O[n], 32);
  }
  const float inv = 1.0f / lsum;

  if (lane == 0) sinv[w] = inv;
  if (kgrp == 0) {
    #pragma unroll
    for (int n = 0; n < 4; ++n) gu[w * 64 + n * 16 + l16] = O[n] * inv;
  }
  __syncthreads();

  // alpha scatter -> ws [b][a][u][h]
  {
    float* ag = ws + WS_ALPHA;
    #pragma unroll
    for (int i = 0; i < 4; ++i) {
      int idx = i * 512 + t;
      int a = idx >> 3, hh = idx & 7;
      ag[(((size_t)b * NA + a) * NU + u) * H + hh] = sc[a * 9 + hh] * sinv[hh];
    }
  }
  out[(size_t)bid * HID + t] = gu[t] + ws[WS_UBASE + (size_t)bid * HID + t];
}

// ---------------------------------------------------------------------------
// Kernel C: per (b, a-quad). 512 threads = 8 waves (wave = head).
// Pass 1: g[a][h][e] = sum_u alpha*edge  (quarter-wave mapping, regs only)
// Pass 2: pu[a][j] = sum_u alpha*UT ; project g by WeT; store.
// ---------------------------------------------------------------------------
__global__ __launch_bounds__(512, 4) void ant_kernel(
    const float* __restrict__ edge, float* __restrict__ ws,
    float* __restrict__ out)
{
  const int bid = blockIdx.x;          // b*64 + aq
  const int b = bid >> 6, a0 = (bid & 63) * 4;
  const int t = threadIdx.x;
  const int w = t >> 6;                // wave = head
  const int lane = t & 63;

  __shared__ float plds[NU * 36];      // 36 KB: [u][h*4 + a], stride 36 (pad)
  __shared__ float galds[4 * H * ED];  // 8 KB : [a][h][e]

  // ---- stage alpha (4 contiguous 8KB slices), transpose to [u][h][a] ----
  {
    const float4* ag = (const float4*)(ws + WS_ALPHA + ((size_t)b * NA + a0) * NU * H);
    #pragma unroll
    for (int r = 0; r < 4; ++r) {
      int idx4 = r * 512 + t;              // [a][u][hq]
      int a = idx4 >> 9, rem = idx4 & 511;
      int uu = rem >> 1, hq = rem & 1;
      float4 vv = ag[idx4];
      float* dst = plds + uu * 36 + hq * 16 + a;
      dst[0]  = vv.x;
      dst[4]  = vv.y;
      dst[8]  = vv.z;
      dst[12] = vv.w;
    }
  }
  __syncthreads();

  // ---- pass 1: g accumulation, quarter-wave (u_loc, e4) ----
  const int u_loc = lane >> 4, e4 = lane & 15;
  float4 g[4] = {{0,0,0,0},{0,0,0,0},{0,0,0,0},{0,0,0,0}};

  {
    const float* ebase0 = edge + (((size_t)b * NU) * NA + a0) * ED + e4 * 4;
    for (int u0 = 0; u0 < NU; u0 += 4) {
      const int uu = u0 + u_loc;
      float4 p4 = *(const float4*)(plds + uu * 36 + w * 4);
      const float* ebase = ebase0 + (size_t)uu * (NA * ED);
      float4 e0 = *(const float4*)(ebase);
      float4 e1 = *(const float4*)(ebase + ED);
      float4 e2 = *(const float4*)(ebase + 2 * ED);
      float4 e3 = *(const float4*)(ebase + 3 * ED);
      g[0].x += p4.x * e0.x; g[0].y += p4.x * e0.y; g[0].z += p4.x * e0.z; g[0].w += p4.x * e0.w;
      g[1].x += p4.y * e1.x; g[1].y += p4.y * e1.y; g[1].z += p4.y * e1.z; g[1].w += p4.y * e1.w;
      g[2].x += p4.z * e2.x; g[2].y += p4.z * e2.y; g[2].z += p4.z * e2.z; g[2].w += p4.z * e2.w;
      g[3].x += p4.w * e3.x; g[3].y += p4.w * e3.y; g[3].z += p4.w * e3.z; g[3].w += p4.w * e3.w;
    }
  }
  // merge across quarter-waves (u_loc)
  #pragma unroll
  for (int al = 0; al < 4; ++al) {
    g[al].x += __shfl_xor(g[al].x, 16); g[al].x += __shfl_xor(g[al].x, 32);
    g[al].y += __shfl_xor(g[al].y, 16); g[al].y += __shfl_xor(g[al].y, 32);
    g[al].z += __shfl_xor(g[al].z, 16); g[al].z += __shfl_xor(g[al].z, 32);
    g[al].w += __shfl_xor(g[al].w, 16); g[al].w += __shfl_xor(g[al].w, 32);
  }
  if (u_loc == 0) {
    #pragma unroll
    for (int al = 0; al < 4; ++al)
      *(float4*)(galds + (al * H + w) * ED + e4 * 4) = g[al];
  }

  // ---- pass 2: pu accumulation (thread t = output col j) ----
  float pu[4] = {0.f, 0.f, 0.f, 0.f};
  {
    const float* UTj = ws + WS_UT + ((size_t)b * HID + t) * 256;
    for (int u0 = 0; u0 < NU; u0 += 4) {
      float4 U4 = *(const float4*)(UTj + u0);
      float4 p0 = *(const float4*)(plds + (u0 + 0) * 36 + w * 4);
      float4 p1 = *(const float4*)(plds + (u0 + 1) * 36 + w * 4);
      float4 p2 = *(const float4*)(plds + (u0 + 2) * 36 + w * 4);
      float4 p3 = *(const float4*)(plds + (u0 + 3) * 36 + w * 4);
      pu[0] += p0.x*U4.x + p1.x*U4.y + p2.x*U4.z + p3.x*U4.w;
      pu[1] += p0.y*U4.x + p1.y*U4.y + p2.y*U4.z + p3.y*U4.w;
      pu[2] += p0.z*U4.x + p1.z*U4.y + p2.z*U4.z + p3.z*U4.w;
      pu[3] += p0.w*U4.x + p1.w*U4.y + p2.w*U4.z + p3.w*U4.w;
    }
  }
  __syncthreads();   // galds ready

  // ---- projection + store ----
  {
    const float* wrow = ws + WS_WET32 + (size_t)t * ED;
    float o[4] = {pu[0], pu[1], pu[2], pu[3]};
    for (int e0 = 0; e0 < ED; e0 += 4) {
      float4 wv = *(const float4*)(wrow + e0);
      #pragma unroll
      for (int al = 0; al < 4; ++al) {
        float4 ga4 = *(const float4*)(galds + (al * H + w) * ED + e0);
        o[al] += ga4.x*wv.x + ga4.y*wv.y + ga4.z*wv.z + ga4.w*wv.w;
      }
    }
    float* outa = out + (size_t)(B_ * NU) * HID;
    #pragma unroll
    for (int al = 0; al < 4; ++al)
      outa[(size_t)((b * NA) + a0 + al) * HID + t] = o[al];
  }
}

// ---------------------------------------------------------------------------
extern "C" void kernel_launch(void* const* d_in, const int* in_sizes, int n_in,
                              void* d_out, int out_size, void* d_ws, size_t ws_size,
                              hipStream_t stream) {
  const float* user = (const float*)d_in[0];
  const float* ant  = (const float*)d_in[1];
  const float* edge = (const float*)d_in[2];
  const float* Wu   = (const float*)d_in[3];
  const float* Wa   = (const float*)d_in[4];
  const float* We   = (const float*)d_in[5];
  const float* av   = (const float*)d_in[6];
  const float* Wres = (const float*)d_in[7];
  float* out = (float*)d_out;
  float* ws  = (float*)d_ws;

  prep_kernel<<<dim3(512, 3), 256, 0, stream>>>(user, ant, Wu, Wa, Wres, ws);
  weprep_kernel<<<dim3(8), 256, 0, stream>>>(We, ws);
  score_user_kernel<<<dim3(B_ * NU), 512, 0, stream>>>(edge, av, ws, out);
  ant_kernel<<<dim3(B_ * 64), 512, 0, stream>>>(edge, ws, out);
}

// Round 7
// 280.869 us; speedup vs baseline: 3.4947x; 1.3017x over previous
//
#include <hip/hip_runtime.h>
#include <math.h>

// Problem constants
constexpr int B_  = 8;
constexpr int NU  = 256;
constexpr int NA  = 256;
constexpr int UD  = 128;
constexpr int ED  = 64;
constexpr int H   = 8;
constexpr int HD  = 64;
constexpr int HID = 512;
constexpr float SLOPE = 0.2f;
constexpr float SCALE = 0.125f;

// ws layout (floats)
constexpr size_t WS_UT    = 0;          // [B][512][256]  (user@Wu)^T : UT[b][j][u]
constexpr size_t WS_AT    = 1048576;    // [B][512][256]  (ant@Wa)^T  : AT[b][j][a]
constexpr size_t WS_UBASE = 2097152;    // [B][NU][512]   user@Wres
constexpr size_t WS_ALPHA = 3145728;    // [B][NA][NU][H] softmax weights
constexpr size_t WS_WET32 = 7340032;    // [512][64] fp32  WeT[j][e] = We[j>>6][e][j&63]
constexpr size_t WS_WET16 = 7372800;    // [512][64] bf16 (as ushort), same layout

typedef __attribute__((ext_vector_type(8))) short short8v;  // 8 bf16
typedef __attribute__((ext_vector_type(4))) float f32x4;

static __device__ __forceinline__ unsigned short f2bf(float f) {
  unsigned int u = __float_as_uint(f);
  unsigned int r = (u + 0x7fffu + ((u >> 16) & 1u)) >> 16;   // RNE
  return (unsigned short)r;
}

// ---------------------------------------------------------------------------
// Kernel A: projections. grid (512, 3), 256 thr, 4 rows/block.
// ---------------------------------------------------------------------------
__global__ __launch_bounds__(256) void prep_kernel(
    const float* __restrict__ user, const float* __restrict__ ant,
    const float* __restrict__ Wu, const float* __restrict__ Wa,
    const float* __restrict__ Wres, float* __restrict__ ws)
{
  const int job = blockIdx.y;
  const int r0  = blockIdx.x * 4;
  const int b   = r0 >> 8, lr = r0 & 255;
  const int t   = threadIdx.x;

  const float* X = (job == 1) ? ant : user;
  const float* W = (job == 0) ? Wu : (job == 1) ? Wa : Wres;

  __shared__ float xs[4][UD];
  #pragma unroll
  for (int i = 0; i < 2; ++i) {
    int idx = i * 256 + t;
    xs[idx >> 7][idx & 127] = X[(size_t)(r0 + (idx >> 7)) * UD + (idx & 127)];
  }
  __syncthreads();

  const int j0 = 2 * t;
  const float* wp;
  int wstride;
  if (job < 2) { wp = W + (size_t)(j0 >> 6) * (UD * HD) + (j0 & 63); wstride = HD; }
  else         { wp = W + j0;                                        wstride = HID; }

  float2 acc[4];
  #pragma unroll
  for (int r = 0; r < 4; ++r) acc[r] = make_float2(0.f, 0.f);

  for (int k = 0; k < UD; ++k) {
    float2 w = *(const float2*)(wp + (size_t)k * wstride);
    #pragma unroll
    for (int r = 0; r < 4; ++r) {
      float x = xs[r][k];
      acc[r].x += x * w.x;
      acc[r].y += x * w.y;
    }
  }

  if (job < 2) {
    float* T = ws + (job == 0 ? WS_UT : WS_AT);
    float4 w0 = make_float4(acc[0].x, acc[1].x, acc[2].x, acc[3].x);
    float4 w1 = make_float4(acc[0].y, acc[1].y, acc[2].y, acc[3].y);
    *(float4*)(T + ((size_t)b * HID + j0)     * 256 + lr) = w0;
    *(float4*)(T + ((size_t)b * HID + j0 + 1) * 256 + lr) = w1;
  } else {
    float* outp = ws + WS_UBASE;
    #pragma unroll
    for (int r = 0; r < 4; ++r)
      *(float2*)(outp + (size_t)(r0 + r) * HID + j0) = acc[r];
  }
}

// ---------------------------------------------------------------------------
// Kernel A2: WeT precompute. 8 blocks (one per head), 256 threads.
// ---------------------------------------------------------------------------
__global__ __launch_bounds__(256) void weprep_kernel(
    const float* __restrict__ We, float* __restrict__ ws)
{
  const int h = blockIdx.x;
  const int t = threadIdx.x;
  __shared__ float lds[ED * HD];

  const float4* src = (const float4*)(We + (size_t)h * ED * HD);
  #pragma unroll
  for (int i = 0; i < 4; ++i) ((float4*)lds)[i * 256 + t] = src[i * 256 + t];
  __syncthreads();

  const int d = t >> 2, q = t & 3;
  float* WeTf = ws + WS_WET32;
  unsigned short* WeT16 = (unsigned short*)(ws + WS_WET16);
  const size_t jrow = (size_t)(h * HD + d) * ED;
  #pragma unroll
  for (int k = 0; k < 16; ++k) {
    const int e = q * 16 + k;
    float v = lds[e * HD + d];
    WeTf[jrow + e]  = v;
    WeT16[jrow + e] = f2bf(v);
  }
}

// ---------------------------------------------------------------------------
// Kernel B: per (b,u). 512 threads = 8 waves; wave w = head w.
// MFMA scores + defer-max softmax accumulation. AT acc-init loads issued
// BEFORE the staging barrier (they hit ws/L2, not LDS) so they drain during
// the barrier's vmcnt(0) wait instead of serially after it.
// ---------------------------------------------------------------------------
__global__ __launch_bounds__(512, 4) void score_user_kernel(
    const float* __restrict__ edge, const float* __restrict__ av,
    float* __restrict__ ws, float* __restrict__ out)
{
  const int bid = blockIdx.x;          // b*NU + u
  const int b = bid >> 8, u = bid & 255;
  const int t = threadIdx.x;

  __shared__ __align__(16) short ebuf[2][32 * ED];  // 2 x 4 KB bf16, swizzled
  __shared__ float sc[NA * 9];                      // exp(score) per [a][h]
  __shared__ float gu[HID];
  __shared__ float sinv[H];

  const float* UT = ws + WS_UT;
  const float* AT = ws + WS_AT;

  const int w    = t >> 6;          // wave = head
  const int lane = t & 63;
  const int l16  = lane & 15;
  const int kgrp = lane >> 4;

  // hoist We fragments (bf16), U cols, av (pre-scaled)
  short8v wf[4][2];
  float   ucol[4];
  float   avv[4];
  const unsigned short* WeT16 = (const unsigned short*)(ws + WS_WET16);
  #pragma unroll
  for (int n = 0; n < 4; ++n) {
    const int j = 64 * w + 16 * n + l16;
    #pragma unroll
    for (int c = 0; c < 2; ++c)
      wf[n][c] = *(const short8v*)(WeT16 + (size_t)j * ED + c * 32 + kgrp * 8);
    ucol[n] = UT[((size_t)b * HID + j) * 256 + u];
    avv[n]  = av[j] * SCALE;
  }

  // staging geometry
  const float4* ep = (const float4*)(edge + (size_t)bid * NA * ED);
  const int srow = t >> 4, sc4 = t & 15;
  const int sbyte = (srow * 128 + sc4 * 8) ^ ((srow & 7) << 4);
  float4 v = ep[t];   // tile 0 edge prefetch

  const float* ATbase = AT + (size_t)b * HID * 256 + kgrp * 4;

  float lsum = 0.f;
  float O[4] = {0.f, 0.f, 0.f, 0.f};

  for (int t8 = 0; t8 < 8; ++t8) {
    const int cur = t8 & 1;
    {
      ushort4 bv = make_ushort4(f2bf(v.x), f2bf(v.y), f2bf(v.z), f2bf(v.w));
      *(ushort4*)((char*)ebuf[cur] + sbyte) = bv;
    }
    if (t8 < 7) v = ep[(t8 + 1) * 512 + t];   // edge prefetch next tile

    // acc init = A loads, issued pre-barrier (complete during barrier drain)
    const int a0 = t8 * 32;
    f32x4 acc[2][4];
    #pragma unroll
    for (int m = 0; m < 2; ++m)
      #pragma unroll
      for (int n = 0; n < 4; ++n) {
        const int j = 64 * w + 16 * n + l16;
        float4 a4 = *(const float4*)(ATbase + (size_t)j * 256 + a0 + m * 16);
        f32x4 vv; vv[0] = a4.x; vv[1] = a4.y; vv[2] = a4.z; vv[3] = a4.w;
        acc[m][n] = vv;
      }

    __syncthreads();

    // A-fragments from LDS
    short8v af[2][2];
    #pragma unroll
    for (int m = 0; m < 2; ++m) {
      #pragma unroll
      for (int c = 0; c < 2; ++c) {
        int row = m * 16 + l16;
        int byte = (row * 128 + (c * 32 + kgrp * 8) * 2) ^ ((row & 7) << 4);
        af[m][c] = *(const short8v*)((const char*)ebuf[cur] + byte);
      }
    }

    #pragma unroll
    for (int c = 0; c < 2; ++c)
      #pragma unroll
      for (int m = 0; m < 2; ++m)
        #pragma unroll
        for (int n = 0; n < 4; ++n)
          acc[m][n] = __builtin_amdgcn_mfma_f32_16x16x32_bf16(
              af[m][c], wf[n][c], acc[m][n], 0, 0, 0);

    // epilogue: leaky(acc+U).av, butterfly, exp (defer-max), accumulate
    #pragma unroll
    for (int m = 0; m < 2; ++m) {
      #pragma unroll
      for (int q = 0; q < 4; ++q) {
        float h0 = 0.f;
        #pragma unroll
        for (int n = 0; n < 4; ++n) {
          float s = acc[m][n][q] + ucol[n];
          s = (s >= 0.f) ? s : SLOPE * s;
          h0 += s * avv[n];
        }
        #pragma unroll
        for (int off = 8; off >= 1; off >>= 1) h0 += __shfl_xor(h0, off);
        float e = __expf(h0);
        lsum += e;
        if (l16 == 0) sc[(a0 + m * 16 + kgrp * 4 + q) * 9 + w] = e;
        #pragma unroll
        for (int n = 0; n < 4; ++n) O[n] += e * acc[m][n][q];
      }
    }
  }

  // final reductions across kgrp
  lsum += __shfl_xor(lsum, 16);
  lsum += __shfl_xor(lsum, 32);
  #pragma unroll
  for (int n = 0; n < 4; ++n) {
    O[n] += __shfl_xor(O[n], 16);
    O[n] += __shfl_xor(O[n], 32);
  }
  const float inv = 1.0f / lsum;

  if (lane == 0) sinv[w] = inv;
  if (kgrp == 0) {
    #pragma unroll
    for (int n = 0; n < 4; ++n) gu[w * 64 + n * 16 + l16] = O[n] * inv;
  }
  __syncthreads();

  // alpha scatter -> ws [b][a][u][h]
  {
    float* ag = ws + WS_ALPHA;
    #pragma unroll
    for (int i = 0; i < 4; ++i) {
      int idx = i * 512 + t;
      int a = idx >> 3, hh = idx & 7;
      ag[(((size_t)b * NA + a) * NU + u) * H + hh] = sc[a * 9 + hh] * sinv[hh];
    }
  }
  out[(size_t)bid * HID + t] = gu[t] + ws[WS_UBASE + (size_t)bid * HID + t];
}

// ---------------------------------------------------------------------------
// Kernel C: per (b, a-quad). 512 threads = 8 waves (wave = head).
// Pass 1: g[a][h][e] = sum_u alpha*edge  (quarter-wave mapping, regs only)
// Pass 2: pu[a][j] = sum_u alpha*UT ; project g by WeT; store.
// ---------------------------------------------------------------------------
__global__ __launch_bounds__(512, 4) void ant_kernel(
    const float* __restrict__ edge, float* __restrict__ ws,
    float* __restrict__ out)
{
  const int bid = blockIdx.x;          // b*64 + aq
  const int b = bid >> 6, a0 = (bid & 63) * 4;
  const int t = threadIdx.x;
  const int w = t >> 6;                // wave = head
  const int lane = t & 63;

  __shared__ float plds[NU * 36];      // 36 KB: [u][h*4 + a], stride 36 (pad)
  __shared__ float galds[4 * H * ED];  // 8 KB : [a][h][e]

  // ---- stage alpha (4 contiguous 8KB slices), transpose to [u][h][a] ----
  {
    const float4* ag = (const float4*)(ws + WS_ALPHA + ((size_t)b * NA + a0) * NU * H);
    #pragma unroll
    for (int r = 0; r < 4; ++r) {
      int idx4 = r * 512 + t;              // [a][u][hq]
      int a = idx4 >> 9, rem = idx4 & 511;
      int uu = rem >> 1, hq = rem & 1;
      float4 vv = ag[idx4];
      float* dst = plds + uu * 36 + hq * 16 + a;
      dst[0]  = vv.x;
      dst[4]  = vv.y;
      dst[8]  = vv.z;
      dst[12] = vv.w;
    }
  }
  __syncthreads();

  // ---- pass 1: g accumulation, quarter-wave (u_loc, e4) ----
  const int u_loc = lane >> 4, e4 = lane & 15;
  float4 g[4] = {{0,0,0,0},{0,0,0,0},{0,0,0,0},{0,0,0,0}};

  {
    const float* ebase0 = edge + (((size_t)b * NU) * NA + a0) * ED + e4 * 4;
    for (int u0 = 0; u0 < NU; u0 += 4) {
      const int uu = u0 + u_loc;
      float4 p4 = *(const float4*)(plds + uu * 36 + w * 4);
      const float* ebase = ebase0 + (size_t)uu * (NA * ED);
      float4 e0 = *(const float4*)(ebase);
      float4 e1 = *(const float4*)(ebase + ED);
      float4 e2 = *(const float4*)(ebase + 2 * ED);
      float4 e3 = *(const float4*)(ebase + 3 * ED);
      g[0].x += p4.x * e0.x; g[0].y += p4.x * e0.y; g[0].z += p4.x * e0.z; g[0].w += p4.x * e0.w;
      g[1].x += p4.y * e1.x; g[1].y += p4.y * e1.y; g[1].z += p4.y * e1.z; g[1].w += p4.y * e1.w;
      g[2].x += p4.z * e2.x; g[2].y += p4.z * e2.y; g[2].z += p4.z * e2.z; g[2].w += p4.z * e2.w;
      g[3].x += p4.w * e3.x; g[3].y += p4.w * e3.y; g[3].z += p4.w * e3.z; g[3].w += p4.w * e3.w;
    }
  }
  // merge across quarter-waves (u_loc)
  #pragma unroll
  for (int al = 0; al < 4; ++al) {
    g[al].x += __shfl_xor(g[al].x, 16); g[al].x += __shfl_xor(g[al].x, 32);
    g[al].y += __shfl_xor(g[al].y, 16); g[al].y += __shfl_xor(g[al].y, 32);
    g[al].z += __shfl_xor(g[al].z, 16); g[al].z += __shfl_xor(g[al].z, 32);
    g[al].w += __shfl_xor(g[al].w, 16); g[al].w += __shfl_xor(g[al].w, 32);
  }
  if (u_loc == 0) {
    #pragma unroll
    for (int al = 0; al < 4; ++al)
      *(float4*)(galds + (al * H + w) * ED + e4 * 4) = g[al];
  }

  // ---- pass 2: pu accumulation (thread t = output col j) ----
  float pu[4] = {0.f, 0.f, 0.f, 0.f};
  {
    const float* UTj = ws + WS_UT + ((size_t)b * HID + t) * 256;
    for (int u0 = 0; u0 < NU; u0 += 4) {
      float4 U4 = *(const float4*)(UTj + u0);
      float4 p0 = *(const float4*)(plds + (u0 + 0) * 36 + w * 4);
      float4 p1 = *(const float4*)(plds + (u0 + 1) * 36 + w * 4);
      float4 p2 = *(const float4*)(plds + (u0 + 2) * 36 + w * 4);
      float4 p3 = *(const float4*)(plds + (u0 + 3) * 36 + w * 4);
      pu[0] += p0.x*U4.x + p1.x*U4.y + p2.x*U4.z + p3.x*U4.w;
      pu[1] += p0.y*U4.x + p1.y*U4.y + p2.y*U4.z + p3.y*U4.w;
      pu[2] += p0.z*U4.x + p1.z*U4.y + p2.z*U4.z + p3.z*U4.w;
      pu[3] += p0.w*U4.x + p1.w*U4.y + p2.w*U4.z + p3.w*U4.w;
    }
  }
  __syncthreads();   // galds ready

  // ---- projection + store ----
  {
    const float* wrow = ws + WS_WET32 + (size_t)t * ED;
    float o[4] = {pu[0], pu[1], pu[2], pu[3]};
    for (int e0 = 0; e0 < ED; e0 += 4) {
      float4 wv = *(const float4*)(wrow + e0);
      #pragma unroll
      for (int al = 0; al < 4; ++al) {
        float4 ga4 = *(const float4*)(galds + (al * H + w) * ED + e0);
        o[al] += ga4.x*wv.x + ga4.y*wv.y + ga4.z*wv.z + ga4.w*wv.w;
      }
    }
    float* outa = out + (size_t)(B_ * NU) * HID;
    #pragma unroll
    for (int al = 0; al < 4; ++al)
      outa[(size_t)((b * NA) + a0 + al) * HID + t] = o[al];
  }
}

// ---------------------------------------------------------------------------
extern "C" void kernel_launch(void* const* d_in, const int* in_sizes, int n_in,
                              void* d_out, int out_size, void* d_ws, size_t ws_size,
                              hipStream_t stream) {
  const float* user = (const float*)d_in[0];
  const float* ant  = (const float*)d_in[1];
  const float* edge = (const float*)d_in[2];
  const float* Wu   = (const float*)d_in[3];
  const float* Wa   = (const float*)d_in[4];
  const float* We   = (const float*)d_in[5];
  const float* av   = (const float*)d_in[6];
  const float* Wres = (const float*)d_in[7];
  float* out = (float*)d_out;
  float* ws  = (float*)d_ws;

  prep_kernel<<<dim3(512, 3), 256, 0, stream>>>(user, ant, Wu, Wa, Wres, ws);
  weprep_kernel<<<dim3(8), 256, 0, stream>>>(We, ws);
  score_user_kernel<<<dim3(B_ * NU), 512, 0, stream>>>(edge, av, ws, out);
  ant_kernel<<<dim3(B_ * 64), 512, 0, stream>>>(edge, ws, out);
}